// Round 17
// baseline (390.553 us; speedup 1.0000x reference)
//
#include <hip/hip_runtime.h>
#include <hip/hip_bf16.h>
#include <cstddef>
#include <cstdint>

#define N_NODESC 100000
#define N_EDGESC 500000
#define NBATCH   512
#define SCAN_CHUNK 1024
#define CONV_KSPLIT 16
#define CONV_KCHUNK 384    // multiple of 32 -> k-octets stay channel-aligned; last split ragged (240)

static inline int divup(int a, int b) { return (a + b - 1) / b; }

typedef __hip_bfloat16 bf16;
typedef short s16x8 __attribute__((ext_vector_type(8)));
typedef float f32x4 __attribute__((ext_vector_type(4)));

__device__ inline float b2f(ushort u) {
    union { uint i; float f; } c; c.i = (uint)u << 16; return c.f;
}
__device__ inline ushort f2bs(float v) {
    bf16 b = __float2bfloat16(v);
    return *reinterpret_cast<ushort*>(&b);
}
__device__ inline void unpack2(uint u, float& a, float& b) {
    union { uint i; float f; } lo, hi;
    lo.i = u << 16; hi.i = u & 0xffff0000u;
    a = lo.f; b = hi.f;
}

// ---------------- zero ints ----------------
__global__ void zero_ints(int* __restrict__ p, int n) {
    int i = blockIdx.x * blockDim.x + threadIdx.x;
    if (i < n) p[i] = 0;
}

// ---------------- degree / dinv ----------------
__global__ void count_deg(const int* __restrict__ dst, int* __restrict__ deg, int e) {
    int i = blockIdx.x * blockDim.x + threadIdx.x;
    if (i < e) atomicAdd(&deg[dst[i]], 1);
}

__global__ void compute_dinv(const int* __restrict__ deg, float* __restrict__ dinv, int n) {
    int i = blockIdx.x * blockDim.x + threadIdx.x;
    if (i < n) dinv[i] = 1.0f / sqrtf((float)deg[i] + 1.0f);
}

// ---------------- exclusive scan (3-phase) ----------------
__global__ void scan_chunks(const int* __restrict__ deg, int* __restrict__ out,
                            int* __restrict__ sums, int n) {
    __shared__ int sdata[256];
    int t = threadIdx.x;
    int base = blockIdx.x * SCAN_CHUNK;
    int v[4];
    int s = 0;
#pragma unroll
    for (int j = 0; j < 4; ++j) {
        int idx = base + t * 4 + j;
        v[j] = s;
        int d = (idx < n) ? deg[idx] : 0;
        s += d;
    }
    int x = s;
    sdata[t] = x;
    __syncthreads();
    for (int off = 1; off < 256; off <<= 1) {
        int y = (t >= off) ? sdata[t - off] : 0;
        __syncthreads();
        x += y;
        sdata[t] = x;
        __syncthreads();
    }
    int thread_excl = x - s;
    if (t == 255) sums[blockIdx.x] = x;
#pragma unroll
    for (int j = 0; j < 4; ++j) {
        int idx = base + t * 4 + j;
        if (idx < n) out[idx] = thread_excl + v[j];
    }
}

__global__ void scan_sums(int* sums, int nchunks) {
    if (threadIdx.x == 0 && blockIdx.x == 0) {
        int acc = 0;
        for (int i = 0; i < nchunks; ++i) { int v = sums[i]; sums[i] = acc; acc += v; }
    }
}

__global__ void finalize_rowptr(int* __restrict__ row_ptr, const int* __restrict__ sums,
                                int* __restrict__ fill, int n, int e) {
    int i = blockIdx.x * blockDim.x + threadIdx.x;
    if (i < n) {
        int v = row_ptr[i] + sums[i / SCAN_CHUNK];
        row_ptr[i] = v;
        fill[i] = v;
    }
    if (i == 0) row_ptr[n] = e;
}

__global__ void fill_csr(const int* __restrict__ src, const int* __restrict__ dst,
                         int* __restrict__ fill, int* __restrict__ csr_src, int e) {
    int i = blockIdx.x * blockDim.x + threadIdx.x;
    if (i < e) {
        int d = dst[i];
        int pos = atomicAdd(&fill[d], 1);
        csr_src[pos] = src[i];
    }
}

// ---------------- fp32 -> bf16 node features, scaled by dinv[node], padded stride ----------------
__global__ void convert_x_bf16(const float* __restrict__ x, const float* __restrict__ dinv,
                               ushort* __restrict__ xbf, int n, int ki, int ld) {
    int i = blockIdx.x * blockDim.x + threadIdx.x;
    int total = n * ld;
    if (i >= total) return;
    int node = i / ld, col = i % ld;
    xbf[i] = (col < ki) ? f2bs(x[(size_t)node * ki + col] * dinv[node]) : (ushort)0;
}

// ---------------- W[KI,KO] fp32 -> Wt[KO,LD] bf16 (transposed, zero-padded) ----------------
__global__ void transpose_w_bf16(const float* __restrict__ W, ushort* __restrict__ Wt,
                                 int ki, int ko, int ld) {
    int i = blockIdx.x * blockDim.x + threadIdx.x;
    int total = ko * ld;
    if (i >= total) return;
    int o = i / ld, k = i % ld;
    Wt[i] = (k < ki) ? f2bs(W[(size_t)k * ko + o]) : (ushort)0;
}

// ---------------- Kxt[32][6000] fp32 -> Kbf[32][6016] bf16 (zero-padded) ----------------
__global__ void convert_k_bf16(const float* __restrict__ Kxt, ushort* __restrict__ Kbf) {
    int i = blockIdx.x * blockDim.x + threadIdx.x;
    if (i >= 32 * 6016) return;
    int o = i / 6016, k = i % 6016;
    Kbf[i] = (k < 6000) ? f2bs(Kxt[(size_t)o * 6000 + k]) : (ushort)0;
}

// ---------------- vectorized GCN aggregation on dinv-prescaled features ----------------
template <int LD>
__global__ void gcn_gather_vec(const ushort* __restrict__ h, const int* __restrict__ row_ptr,
                               const int* __restrict__ csr_src, const float* __restrict__ dinv,
                               ushort* __restrict__ agg, int n) {
    constexpr int TPN = LD / 8;
    int gid = blockIdx.x * blockDim.x + threadIdx.x;
    int node = gid / TPN, oct = gid % TPN;
    if (node >= n) return;
    float dn = dinv[node];
    int e0 = row_ptr[node], e1 = row_ptr[node + 1];
    float acc[8];
    {   // self term: h'[node]
        uint4 v = *reinterpret_cast<const uint4*>(&h[(size_t)node * LD + oct * 8]);
        unpack2(v.x, acc[0], acc[1]);
        unpack2(v.y, acc[2], acc[3]);
        unpack2(v.z, acc[4], acc[5]);
        unpack2(v.w, acc[6], acc[7]);
    }
    for (int e = e0; e < e1; ++e) {
        int s = csr_src[e];
        uint4 v = *reinterpret_cast<const uint4*>(&h[(size_t)s * LD + oct * 8]);
        float a, b;
        unpack2(v.x, a, b); acc[0] += a; acc[1] += b;
        unpack2(v.y, a, b); acc[2] += a; acc[3] += b;
        unpack2(v.z, a, b); acc[4] += a; acc[5] += b;
        unpack2(v.w, a, b); acc[6] += a; acc[7] += b;
    }
    uint4 o;
    o.x = (uint)f2bs(acc[0] * dn) | ((uint)f2bs(acc[1] * dn) << 16);
    o.y = (uint)f2bs(acc[2] * dn) | ((uint)f2bs(acc[3] * dn) << 16);
    o.z = (uint)f2bs(acc[4] * dn) | ((uint)f2bs(acc[5] * dn) << 16);
    o.w = (uint)f2bs(acc[6] * dn) | ((uint)f2bs(acc[7] * dn) << 16);
    *reinterpret_cast<uint4*>(&agg[(size_t)node * LD + oct * 8]) = o;
}

// ---------------- bf16 MFMA GEMM: C = A @ Wt^T (+bias+relu)(*rowscale), bf16 out ----------------
template <int KI, int LDA, int KO, int LDC, int NBY, bool SCALEROW>
__global__ __launch_bounds__(256) void gemm_mfma(const ushort* __restrict__ A,
                                                 const ushort* __restrict__ Bt,
                                                 const float* __restrict__ bias,
                                                 const float* __restrict__ rowscale,
                                                 ushort* __restrict__ C, int n) {
    __shared__ ushort sA[64][40];
    __shared__ ushort sB[64][40];
    const int t = threadIdx.x;
    const int row0 = (blockIdx.x / NBY) * 64;
    const int col0 = (blockIdx.x % NBY) * 64;
    const int wid = t >> 6, lane = t & 63;
    const int wr = wid >> 1, wc = wid & 1;
    const int lrow = lane & 15;
    const int kgrp = lane >> 4;
    const int srr = t >> 2;      // staging row 0..63
    const int skq = t & 3;       // staging k-octet
    f32x4 acc[2][2];
#pragma unroll
    for (int i = 0; i < 2; ++i)
#pragma unroll
        for (int j = 0; j < 2; ++j) acc[i][j] = (f32x4)0.f;

    const int nk = (KI + 31) / 32;
    for (int ks = 0; ks < nk; ++ks) {
        const int kbase = ks * 32 + skq * 8;
        {   // stage A tile (64 rows x 32 k)
            int grow = row0 + srr;
            uint4 v = {0, 0, 0, 0};
            if (grow < n && kbase < LDA)
                v = *reinterpret_cast<const uint4*>(&A[(size_t)grow * LDA + kbase]);
            *reinterpret_cast<uint4*>(&sA[srr][skq * 8]) = v;
        }
        {   // stage B tile (64 cols x 32 k)
            int gcol = col0 + srr;
            uint4 v = {0, 0, 0, 0};
            if (gcol < KO && kbase < LDA)
                v = *reinterpret_cast<const uint4*>(&Bt[(size_t)gcol * LDA + kbase]);
            *reinterpret_cast<uint4*>(&sB[srr][skq * 8]) = v;
        }
        __syncthreads();
        s16x8 a0 = *reinterpret_cast<const s16x8*>(&sA[wr * 32 + lrow][kgrp * 8]);
        s16x8 a1 = *reinterpret_cast<const s16x8*>(&sA[wr * 32 + 16 + lrow][kgrp * 8]);
        s16x8 b0 = *reinterpret_cast<const s16x8*>(&sB[wc * 32 + lrow][kgrp * 8]);
        s16x8 b1 = *reinterpret_cast<const s16x8*>(&sB[wc * 32 + 16 + lrow][kgrp * 8]);
        acc[0][0] = __builtin_amdgcn_mfma_f32_16x16x32_bf16(a0, b0, acc[0][0], 0, 0, 0);
        acc[0][1] = __builtin_amdgcn_mfma_f32_16x16x32_bf16(a0, b1, acc[0][1], 0, 0, 0);
        acc[1][0] = __builtin_amdgcn_mfma_f32_16x16x32_bf16(a1, b0, acc[1][0], 0, 0, 0);
        acc[1][1] = __builtin_amdgcn_mfma_f32_16x16x32_bf16(a1, b1, acc[1][1], 0, 0, 0);
        __syncthreads();
    }
#pragma unroll
    for (int fr = 0; fr < 2; ++fr)
#pragma unroll
        for (int fc = 0; fc < 2; ++fc)
#pragma unroll
            for (int r = 0; r < 4; ++r) {
                int row = row0 + wr * 32 + fr * 16 + kgrp * 4 + r;
                int col = col0 + wc * 32 + fc * 16 + lrow;
                if (row < n && col < LDC) {
                    float v = acc[fr][fc][r];
                    ushort o = 0;
                    if (col < KO) {
                        v = fmaxf(v + bias[col], 0.f);
                        if (SCALEROW) v *= rowscale[row];
                        o = f2bs(v);
                    }
                    C[(size_t)row * LDC + col] = o;
                }
            }
}

// ---------------- layer-3 MFMA GEMM with FUSED segment-max pool (XCD-chunked grid) ----------------
__global__ __launch_bounds__(256) void gemm_mfma_segmax(const ushort* __restrict__ A,
                                                        const ushort* __restrict__ Bt,
                                                        const float* __restrict__ bias,
                                                        const int* __restrict__ batch,
                                                        uint* __restrict__ g0u, int n) {
    constexpr int KI = 156, LDA = 160, KO = 312, NBY = 5;
    constexpr int NRG = (N_NODESC + 63) / 64;        // 1563 row-groups
    constexpr int Q = NRG / 8, R = NRG % 8;          // chunks of 196 (xcd<R) or 195
    __shared__ ushort sA[64][40];
    __shared__ ushort sB[64][40];
    __shared__ ushort sC[64][66];
    __shared__ int sbatch[64];
    const int bid = blockIdx.x;
    const int xcd = bid & 7;
    const int idx = bid >> 3;
    const int chunk = Q + (xcd < R ? 1 : 0);
    const int rgl = idx / NBY;
    if (rgl >= chunk) return;                        // uniform idle block (pre-barrier)
    const int rg = xcd * Q + min(xcd, R) + rgl;
    const int row0 = rg * 64;
    const int col0 = (idx % NBY) * 64;
    const int t = threadIdx.x;
    const int wid = t >> 6, lane = t & 63;
    const int wr = wid >> 1, wc = wid & 1;
    const int lrow = lane & 15;
    const int kgrp = lane >> 4;
    const int srr = t >> 2;
    const int skq = t & 3;
    if (t < 64) sbatch[t] = (row0 + t < n) ? batch[row0 + t] : -1;
    f32x4 acc[2][2];
#pragma unroll
    for (int i = 0; i < 2; ++i)
#pragma unroll
        for (int j = 0; j < 2; ++j) acc[i][j] = (f32x4)0.f;

    const int nk = (KI + 31) / 32;
    for (int ks = 0; ks < nk; ++ks) {
        const int kbase = ks * 32 + skq * 8;
        {
            int grow = row0 + srr;
            uint4 v = {0, 0, 0, 0};
            if (grow < n && kbase < LDA)
                v = *reinterpret_cast<const uint4*>(&A[(size_t)grow * LDA + kbase]);
            *reinterpret_cast<uint4*>(&sA[srr][skq * 8]) = v;
        }
        {
            int gcol = col0 + srr;
            uint4 v = {0, 0, 0, 0};
            if (gcol < KO && kbase < LDA)
                v = *reinterpret_cast<const uint4*>(&Bt[(size_t)gcol * LDA + kbase]);
            *reinterpret_cast<uint4*>(&sB[srr][skq * 8]) = v;
        }
        __syncthreads();
        s16x8 a0 = *reinterpret_cast<const s16x8*>(&sA[wr * 32 + lrow][kgrp * 8]);
        s16x8 a1 = *reinterpret_cast<const s16x8*>(&sA[wr * 32 + 16 + lrow][kgrp * 8]);
        s16x8 b0 = *reinterpret_cast<const s16x8*>(&sB[wc * 32 + lrow][kgrp * 8]);
        s16x8 b1 = *reinterpret_cast<const s16x8*>(&sB[wc * 32 + 16 + lrow][kgrp * 8]);
        acc[0][0] = __builtin_amdgcn_mfma_f32_16x16x32_bf16(a0, b0, acc[0][0], 0, 0, 0);
        acc[0][1] = __builtin_amdgcn_mfma_f32_16x16x32_bf16(a0, b1, acc[0][1], 0, 0, 0);
        acc[1][0] = __builtin_amdgcn_mfma_f32_16x16x32_bf16(a1, b0, acc[1][0], 0, 0, 0);
        acc[1][1] = __builtin_amdgcn_mfma_f32_16x16x32_bf16(a1, b1, acc[1][1], 0, 0, 0);
        __syncthreads();
    }
#pragma unroll
    for (int fr = 0; fr < 2; ++fr)
#pragma unroll
        for (int fc = 0; fc < 2; ++fc)
#pragma unroll
            for (int r = 0; r < 4; ++r) {
                int lr = wr * 32 + fr * 16 + kgrp * 4 + r;
                int lc = wc * 32 + fc * 16 + lrow;
                int gcol = col0 + lc;
                ushort o = 0;
                if (gcol < KO) o = f2bs(fmaxf(acc[fr][fc][r] + bias[gcol], 0.f));
                sC[lr][lc] = o;
            }
    __syncthreads();
    {
        int col = t & 63, q = t >> 6;
        int gcol = col0 + col;
        if (gcol < KO) {
            int base = q * 16;
            int cur = sbatch[base];
            float m = 0.f;
#pragma unroll 4
            for (int i = 0; i < 16; ++i) {
                int b = sbatch[base + i];
                if (b != cur) {
                    if (cur >= 0) atomicMax(&g0u[(size_t)cur * KO + gcol], __float_as_uint(m));
                    m = 0.f;
                    cur = b;
                }
                m = fmaxf(m, b2f(sC[base + i][col]));
            }
            if (cur >= 0) atomicMax(&g0u[(size_t)cur * KO + gcol], __float_as_uint(m));
        }
    }
}

// ---------------- head GEMM: K-split, 32x64 tile, fp32 partials ----------------
template <int KI, int KO, int KS>
__global__ __launch_bounds__(256) void gemm_head(const float* __restrict__ A,
                                                 const float* __restrict__ W,
                                                 float* __restrict__ partial, int n) {
    __shared__ float sA[16][34];
    __shared__ float sW[16][68];
    const int t = threadIdx.x;
    const int row0 = blockIdx.x * 32;
    const int col0 = blockIdx.y * 64;
    const int z = blockIdx.z;
    const int kbeg = z * KS;
    const int kend = min(KI, kbeg + KS);
    const int r0 = (t >> 4) * 2;   // 0..30 (even)
    const int c0 = (t & 15) * 4;   // 0..60 (quad)
    float acc[2][4] = {};
    for (int k0 = kbeg; k0 < kend; k0 += 16) {
        {   // stage A: 32 rows x 16 k
            int row = t >> 3, kk = (t & 7) * 2;
            int grow = row0 + row;
#pragma unroll
            for (int j = 0; j < 2; ++j) {
                float v = 0.f;
                if (grow < n && (k0 + kk + j) < kend) v = A[(size_t)grow * KI + k0 + kk + j];
                sA[kk + j][row] = v;
            }
        }
        {   // stage W: 16 k x 64 cols
            int kk = t >> 4, cc = (t & 15) * 4;
#pragma unroll
            for (int j = 0; j < 4; ++j) {
                float v = 0.f;
                if ((k0 + kk) < kend) v = W[(size_t)(k0 + kk) * KO + col0 + cc + j];
                sW[kk][cc + j] = v;
            }
        }
        __syncthreads();
#pragma unroll 8
        for (int k = 0; k < 16; ++k) {
            float2 a = *reinterpret_cast<const float2*>(&sA[k][r0]);
            float4 w = *reinterpret_cast<const float4*>(&sW[k][c0]);
            acc[0][0] = fmaf(a.x, w.x, acc[0][0]); acc[0][1] = fmaf(a.x, w.y, acc[0][1]);
            acc[0][2] = fmaf(a.x, w.z, acc[0][2]); acc[0][3] = fmaf(a.x, w.w, acc[0][3]);
            acc[1][0] = fmaf(a.y, w.x, acc[1][0]); acc[1][1] = fmaf(a.y, w.y, acc[1][1]);
            acc[1][2] = fmaf(a.y, w.z, acc[1][2]); acc[1][3] = fmaf(a.y, w.w, acc[1][3]);
        }
        __syncthreads();
    }
#pragma unroll
    for (int ri = 0; ri < 2; ++ri) {
        int row = row0 + r0 + ri;
        if (row >= n) continue;
        *reinterpret_cast<float4*>(&partial[((size_t)z * n + row) * KO + col0 + c0]) =
            make_float4(acc[ri][0], acc[ri][1], acc[ri][2], acc[ri][3]);
    }
}

// sum partials over splits + bias (+relu), scatter into C[row*ldc + col_off + col]
template <int NS, bool RELU>
__global__ void head_reduce(const float* __restrict__ partial, const float* __restrict__ bias,
                            float* __restrict__ C, int n, int KO, int ldc, int col_off) {
    int j = blockIdx.x * blockDim.x + threadIdx.x;
    if (j >= n * KO) return;
    int row = j / KO, col = j % KO;
    float acc = bias[col];
#pragma unroll
    for (int s = 0; s < NS; ++s) acc += partial[((size_t)s * n + row) * KO + col];
    if (RELU) acc = fmaxf(acc, 0.f);
    C[(size_t)row * ldc + col_off + col] = acc;
}

// ---------------- Conv1d as implicit GEMM via MFMA, 2-step unrolled (MLP x2) ----------------
// Per iteration: issue BOTH substeps' global loads first (4 dwordx4 in flight/thread),
// then convert+LDS, one barrier pair, 4 MFMA per wave.
__global__ __launch_bounds__(256) void conv_mfma(const float* __restrict__ T,
                                                 const ushort* __restrict__ Kbf,
                                                 float* __restrict__ partial) {
    __shared__ ushort sA[2][64][40];
    __shared__ ushort sB[2][32][40];
    const int t = threadIdx.x;
    const int row0 = blockIdx.x * 64;
    const int split = blockIdx.y;
    const int kbeg = split * CONV_KCHUNK;
    const int kend = min(6000, kbeg + CONV_KCHUNK);
    const int wid = t >> 6, lane = t & 63;
    const int lrow = lane & 15, kgrp = lane >> 4;
    const int rr = t >> 2, kq = t & 3;
    const int grow = row0 + rr;                  // < 6144 always
    const int bb = grow / 12, hh = grow % 12;
    const float* tbase = &T[(size_t)bb * 14250 + hh];
    f32x4 acc0 = (f32x4)0.f, acc1 = (f32x4)0.f;
    for (int k0 = kbeg; k0 < kend; k0 += 64) {
        // ---- issue all global loads for both substeps (A) ----
        float va[2][8];
#pragma unroll
        for (int s = 0; s < 2; ++s) {
            int kb = k0 + s * 32 + kq * 8;       // multiple of 8
            const float* tp = tbase + (size_t)(kb >> 3) * 19;
#pragma unroll
            for (int j = 0; j < 8; ++j)
                va[s][j] = (kb + j < kend) ? tp[j] : 0.f;
        }
        // ---- B loads (Kbf padded to 6016; max idx = 5952+56+8 = 6016 OK) ----
        uint4 vb[2];
        if (t < 128) {
            int o = t >> 2, q2 = t & 3;
#pragma unroll
            for (int s = 0; s < 2; ++s)
                vb[s] = *reinterpret_cast<const uint4*>(&Kbf[(size_t)o * 6016 + k0 + s * 32 + q2 * 8]);
        }
        // ---- convert + LDS writes ----
#pragma unroll
        for (int s = 0; s < 2; ++s) {
            uint4 v;
            v.x = (uint)f2bs(va[s][0]) | ((uint)f2bs(va[s][1]) << 16);
            v.y = (uint)f2bs(va[s][2]) | ((uint)f2bs(va[s][3]) << 16);
            v.z = (uint)f2bs(va[s][4]) | ((uint)f2bs(va[s][5]) << 16);
            v.w = (uint)f2bs(va[s][6]) | ((uint)f2bs(va[s][7]) << 16);
            *reinterpret_cast<uint4*>(&sA[s][rr][kq * 8]) = v;
        }
        if (t < 128) {
            int o = t >> 2, q2 = t & 3;
#pragma unroll
            for (int s = 0; s < 2; ++s)
                *reinterpret_cast<uint4*>(&sB[s][o][q2 * 8]) = vb[s];
        }
        __syncthreads();
#pragma unroll
        for (int s = 0; s < 2; ++s) {
            s16x8 a0 = *reinterpret_cast<const s16x8*>(&sA[s][wid * 16 + lrow][kgrp * 8]);
            s16x8 b0 = *reinterpret_cast<const s16x8*>(&sB[s][lrow][kgrp * 8]);
            s16x8 b1 = *reinterpret_cast<const s16x8*>(&sB[s][16 + lrow][kgrp * 8]);
            acc0 = __builtin_amdgcn_mfma_f32_16x16x32_bf16(a0, b0, acc0, 0, 0, 0);
            acc1 = __builtin_amdgcn_mfma_f32_16x16x32_bf16(a0, b1, acc1, 0, 0, 0);
        }
        __syncthreads();
    }
#pragma unroll
    for (int r = 0; r < 4; ++r) {
        int row = row0 + wid * 16 + kgrp * 4 + r;   // C/D: row=(lane>>4)*4+reg, col=lane&15
        int b = row / 12, h = row % 12;
        partial[(((size_t)split * NBATCH + b) * 32 + lrow) * 12 + h] = acc0[r];
        partial[(((size_t)split * NBATCH + b) * 32 + (16 + lrow)) * 12 + h] = acc1[r];
    }
}

__global__ void conv_reduce(const float* __restrict__ partial, const float* __restrict__ bxt,
                            float* __restrict__ convb) {
    int j = blockIdx.x * blockDim.x + threadIdx.x;
    if (j >= NBATCH * 384) return;
    int b = j / 384, rem = j % 384;
    int o = rem / 12, h = rem % 12;
    float acc = bxt[o];
#pragma unroll
    for (int s = 0; s < CONV_KSPLIT; ++s)
        acc += partial[(((size_t)s * NBATCH + b) * 32 + o) * 12 + h];
    convb[j] = acc;
}

// ---------------- final [512,512] @ [512,1] ----------------
__global__ void final_out(const float* __restrict__ f2, const float* __restrict__ Wo,
                          const float* __restrict__ bo, float* __restrict__ out) {
    int row = blockIdx.x * (blockDim.x / 64) + (threadIdx.x / 64);
    int lane = threadIdx.x & 63;
    if (row >= NBATCH) return;
    float acc = 0.f;
    for (int k = lane; k < 512; k += 64) acc = fmaf(f2[(size_t)row * 512 + k], Wo[k], acc);
#pragma unroll
    for (int off = 32; off > 0; off >>= 1) acc += __shfl_down(acc, off);
    if (lane == 0) out[row] = acc + bo[0];
}

extern "C" void kernel_launch(void* const* d_in, const int* in_sizes, int n_in,
                              void* d_out, int out_size, void* d_ws, size_t ws_size,
                              hipStream_t stream) {
    (void)in_sizes; (void)n_in; (void)out_size; (void)ws_size;
    const float* x     = (const float*)d_in[0];
    const int*   ei    = (const int*)d_in[1];
    const int*   batch = (const int*)d_in[2];
    const float* T     = (const float*)d_in[3];
    const float* W1 = (const float*)d_in[4];   const float* b1 = (const float*)d_in[5];
    const float* W2 = (const float*)d_in[6];   const float* b2 = (const float*)d_in[7];
    const float* W3 = (const float*)d_in[8];   const float* b3 = (const float*)d_in[9];
    const float* Wg1 = (const float*)d_in[10]; const float* bg1 = (const float*)d_in[11];
    const float* Wg2 = (const float*)d_in[12]; const float* bg2 = (const float*)d_in[13];
    const float* Kxt = (const float*)d_in[14]; const float* bxt = (const float*)d_in[15];
    const float* Wxt = (const float*)d_in[16]; const float* bxt2 = (const float*)d_in[17];
    const float* Wf1 = (const float*)d_in[18]; const float* bf1 = (const float*)d_in[19];
    const float* Wf2 = (const float*)d_in[20]; const float* bf2 = (const float*)d_in[21];
    const float* Wo = (const float*)d_in[22];  const float* bo = (const float*)d_in[23];
    const int* src = ei;
    const int* dst = ei + N_EDGESC;

    char* ws = (char*)d_ws;
    size_t off = 0;
    auto alloc = [&](size_t bytes) -> void* {
        void* p = ws + off;
        off += (bytes + 255) & ~(size_t)255;
        return p;
    };
    int*   deg      = (int*)alloc((size_t)N_NODESC * 4);
    float* dinv     = (float*)alloc((size_t)N_NODESC * 4);
    int*   row_ptr  = (int*)alloc((size_t)(N_NODESC + 1) * 4);
    int*   fillc    = (int*)alloc((size_t)N_NODESC * 4);
    int*   csr_src  = (int*)alloc((size_t)N_EDGESC * 4);
    int*   csums    = (int*)alloc((size_t)4096 * 4);
    float* g0       = (float*)alloc((size_t)NBATCH * 312 * 4);
    float* g1       = (float*)alloc((size_t)NBATCH * 1024 * 4);
    float* convb    = (float*)alloc((size_t)NBATCH * 384 * 4);
    float* xc       = (float*)alloc((size_t)NBATCH * 256 * 4);
    float* f1       = (float*)alloc((size_t)NBATCH * 1024 * 4);
    float* f2       = (float*)alloc((size_t)NBATCH * 512 * 4);
    float* cpart    = (float*)alloc((size_t)CONV_KSPLIT * NBATCH * 32 * 12 * 4);
    float* hpart    = (float*)alloc((size_t)4 * NBATCH * 1024 * 4);   // 8MB: max NS*n*KO
    ushort* xbf     = (ushort*)alloc((size_t)N_NODESC * 80 * 2);   // x' (80) -> later h1' (80)
    ushort* aggbuf  = (ushort*)alloc((size_t)N_NODESC * 160 * 2);  // agg1/2 (80), agg3 (160)
    ushort* hbuf    = (ushort*)alloc((size_t)N_NODESC * 160 * 2);  // h2' (160)
    ushort* Wt1     = (ushort*)alloc((size_t)78 * 80 * 2);
    ushort* Wt2     = (ushort*)alloc((size_t)156 * 80 * 2);
    ushort* Wt3     = (ushort*)alloc((size_t)312 * 160 * 2);
    ushort* Kbf     = (ushort*)alloc((size_t)32 * 6016 * 2);
    float* out      = (float*)d_out;

    const int TPB = 256;

    // ---- graph structure ----
    zero_ints<<<divup(N_NODESC, TPB), TPB, 0, stream>>>(deg, N_NODESC);
    count_deg<<<divup(N_EDGESC, TPB), TPB, 0, stream>>>(dst, deg, N_EDGESC);
    compute_dinv<<<divup(N_NODESC, TPB), TPB, 0, stream>>>(deg, dinv, N_NODESC);
    int nchunks = divup(N_NODESC, SCAN_CHUNK);
    scan_chunks<<<nchunks, 256, 0, stream>>>(deg, row_ptr, csums, N_NODESC);
    scan_sums<<<1, 64, 0, stream>>>(csums, nchunks);
    finalize_rowptr<<<divup(N_NODESC, TPB), TPB, 0, stream>>>(row_ptr, csums, fillc, N_NODESC, N_EDGESC);
    fill_csr<<<divup(N_EDGESC, TPB), TPB, 0, stream>>>(src, dst, fillc, csr_src, N_EDGESC);

    // ---- bf16 conversions (x folded with dinv) ----
    convert_x_bf16<<<divup(N_NODESC * 80, TPB), TPB, 0, stream>>>(x, dinv, xbf, N_NODESC, 78, 80);
    transpose_w_bf16<<<divup(78 * 80, TPB), TPB, 0, stream>>>(W1, Wt1, 78, 78, 80);
    transpose_w_bf16<<<divup(156 * 80, TPB), TPB, 0, stream>>>(W2, Wt2, 78, 156, 80);
    transpose_w_bf16<<<divup(312 * 160, TPB), TPB, 0, stream>>>(W3, Wt3, 156, 312, 160);
    convert_k_bf16<<<divup(32 * 6016, TPB), TPB, 0, stream>>>(Kxt, Kbf);

    // ---- GCN layer 1: agg(x') -> gemm(+bias+relu, *dinv) -> h1' (LD 80) ----
    gcn_gather_vec<80><<<divup(N_NODESC * 10, TPB), TPB, 0, stream>>>(
        xbf, row_ptr, csr_src, dinv, aggbuf, N_NODESC);
    gemm_mfma<78, 80, 78, 80, 2, true><<<divup(N_NODESC, 64) * 2, 256, 0, stream>>>(
        aggbuf, Wt1, b1, dinv, xbf, N_NODESC);   // h1' overwrites xbf

    // ---- GCN layer 2: agg(h1') -> gemm(*dinv) -> h2' (LD 160) ----
    gcn_gather_vec<80><<<divup(N_NODESC * 10, TPB), TPB, 0, stream>>>(
        xbf, row_ptr, csr_src, dinv, aggbuf, N_NODESC);
    gemm_mfma<78, 80, 156, 160, 3, true><<<divup(N_NODESC, 64) * 3, 256, 0, stream>>>(
        aggbuf, Wt2, b2, dinv, hbuf, N_NODESC);

    // ---- GCN layer 3: agg(h2') -> gemm + FUSED segment-max (XCD-chunked grid) ----
    gcn_gather_vec<160><<<divup(N_NODESC * 20, TPB), TPB, 0, stream>>>(
        hbuf, row_ptr, csr_src, dinv, aggbuf, N_NODESC);
    zero_ints<<<divup(NBATCH * 312, TPB), TPB, 0, stream>>>((int*)g0, NBATCH * 312);
    gemm_mfma_segmax<<<8 * 196 * 5, 256, 0, stream>>>(
        aggbuf, Wt3, b3, batch, (uint*)g0, N_NODESC);

    // ---- graph head: g1 = relu(g0 @ Wg1 + bg1) — 3 K-splits, 768 blocks ----
    gemm_head<312, 1024, 112><<<dim3(16, 16, 3), 256, 0, stream>>>(g0, Wg1, hpart, NBATCH);
    head_reduce<3, true><<<divup(NBATCH * 1024, TPB), TPB, 0, stream>>>(
        hpart, bg1, g1, NBATCH, 1024, 1024, 0);
    // xc[:, :128] = g1 @ Wg2 + bg2 — 16 K-splits, 512 blocks
    gemm_head<1024, 128, 64><<<dim3(16, 2, 16), 256, 0, stream>>>(g1, Wg2, hpart, NBATCH);
    head_reduce<16, false><<<divup(NBATCH * 128, TPB), TPB, 0, stream>>>(
        hpart, bg2, xc, NBATCH, 128, 256, 0);

    // ---- protein branch: implicit-GEMM conv via MFMA (2-step unrolled) ----
    conv_mfma<<<dim3(6144 / 64, CONV_KSPLIT), 256, 0, stream>>>(T, Kbf, cpart);
    conv_reduce<<<divup(NBATCH * 384, TPB), TPB, 0, stream>>>(cpart, bxt, convb);
    // xc[:, 128:] = convb @ Wxt + bxt2 — 16 K-splits, 512 blocks
    gemm_head<384, 128, 24><<<dim3(16, 2, 16), 256, 0, stream>>>(convb, Wxt, hpart, NBATCH);
    head_reduce<16, false><<<divup(NBATCH * 128, TPB), TPB, 0, stream>>>(
        hpart, bxt2, xc, NBATCH, 128, 256, 128);

    // ---- fusion MLP: f1 — 4 K-splits, 1024 blocks; f2 — 8 K-splits, 1024 blocks ----
    gemm_head<256, 1024, 64><<<dim3(16, 16, 4), 256, 0, stream>>>(xc, Wf1, hpart, NBATCH);
    head_reduce<4, true><<<divup(NBATCH * 1024, TPB), TPB, 0, stream>>>(
        hpart, bf1, f1, NBATCH, 1024, 1024, 0);
    gemm_head<1024, 512, 128><<<dim3(16, 8, 8), 256, 0, stream>>>(f1, Wf2, hpart, NBATCH);
    head_reduce<8, true><<<divup(NBATCH * 512, TPB), TPB, 0, stream>>>(
        hpart, bf2, f2, NBATCH, 512, 512, 0);
    final_out<<<divup(NBATCH, 4), 256, 0, stream>>>(f2, Wo, bo, out);
}

// Round 18
// 381.274 us; speedup vs baseline: 1.0243x; 1.0243x over previous
//
#include <hip/hip_runtime.h>
#include <hip/hip_bf16.h>
#include <cstddef>
#include <cstdint>

#define N_NODESC 100000
#define N_EDGESC 500000
#define NBATCH   512
#define SCAN_CHUNK 1024
#define CONV_KSPLIT 16
#define CONV_KCHUNK 384    // multiple of 32 -> k-octets stay channel-aligned; last split ragged (240)

static inline int divup(int a, int b) { return (a + b - 1) / b; }

typedef __hip_bfloat16 bf16;
typedef short s16x8 __attribute__((ext_vector_type(8)));
typedef float f32x4 __attribute__((ext_vector_type(4)));

__device__ inline float b2f(ushort u) {
    union { uint i; float f; } c; c.i = (uint)u << 16; return c.f;
}
__device__ inline ushort f2bs(float v) {
    bf16 b = __float2bfloat16(v);
    return *reinterpret_cast<ushort*>(&b);
}
__device__ inline void unpack2(uint u, float& a, float& b) {
    union { uint i; float f; } lo, hi;
    lo.i = u << 16; hi.i = u & 0xffff0000u;
    a = lo.f; b = hi.f;
}

// ---------------- zero ints ----------------
__global__ void zero_ints(int* __restrict__ p, int n) {
    int i = blockIdx.x * blockDim.x + threadIdx.x;
    if (i < n) p[i] = 0;
}

// ---------------- degree / dinv ----------------
__global__ void count_deg(const int* __restrict__ dst, int* __restrict__ deg, int e) {
    int i = blockIdx.x * blockDim.x + threadIdx.x;
    if (i < e) atomicAdd(&deg[dst[i]], 1);
}

__global__ void compute_dinv(const int* __restrict__ deg, float* __restrict__ dinv, int n) {
    int i = blockIdx.x * blockDim.x + threadIdx.x;
    if (i < n) dinv[i] = 1.0f / sqrtf((float)deg[i] + 1.0f);
}

// ---------------- exclusive scan (3-phase) ----------------
__global__ void scan_chunks(const int* __restrict__ deg, int* __restrict__ out,
                            int* __restrict__ sums, int n) {
    __shared__ int sdata[256];
    int t = threadIdx.x;
    int base = blockIdx.x * SCAN_CHUNK;
    int v[4];
    int s = 0;
#pragma unroll
    for (int j = 0; j < 4; ++j) {
        int idx = base + t * 4 + j;
        v[j] = s;
        int d = (idx < n) ? deg[idx] : 0;
        s += d;
    }
    int x = s;
    sdata[t] = x;
    __syncthreads();
    for (int off = 1; off < 256; off <<= 1) {
        int y = (t >= off) ? sdata[t - off] : 0;
        __syncthreads();
        x += y;
        sdata[t] = x;
        __syncthreads();
    }
    int thread_excl = x - s;
    if (t == 255) sums[blockIdx.x] = x;
#pragma unroll
    for (int j = 0; j < 4; ++j) {
        int idx = base + t * 4 + j;
        if (idx < n) out[idx] = thread_excl + v[j];
    }
}

__global__ void scan_sums(int* sums, int nchunks) {
    if (threadIdx.x == 0 && blockIdx.x == 0) {
        int acc = 0;
        for (int i = 0; i < nchunks; ++i) { int v = sums[i]; sums[i] = acc; acc += v; }
    }
}

__global__ void finalize_rowptr(int* __restrict__ row_ptr, const int* __restrict__ sums,
                                int* __restrict__ fill, int n, int e) {
    int i = blockIdx.x * blockDim.x + threadIdx.x;
    if (i < n) {
        int v = row_ptr[i] + sums[i / SCAN_CHUNK];
        row_ptr[i] = v;
        fill[i] = v;
    }
    if (i == 0) row_ptr[n] = e;
}

__global__ void fill_csr(const int* __restrict__ src, const int* __restrict__ dst,
                         int* __restrict__ fill, int* __restrict__ csr_src, int e) {
    int i = blockIdx.x * blockDim.x + threadIdx.x;
    if (i < e) {
        int d = dst[i];
        int pos = atomicAdd(&fill[d], 1);
        csr_src[pos] = src[i];
    }
}

// ---------------- fp32 -> bf16 node features, scaled by dinv[node], padded stride ----------------
__global__ void convert_x_bf16(const float* __restrict__ x, const float* __restrict__ dinv,
                               ushort* __restrict__ xbf, int n, int ki, int ld) {
    int i = blockIdx.x * blockDim.x + threadIdx.x;
    int total = n * ld;
    if (i >= total) return;
    int node = i / ld, col = i % ld;
    xbf[i] = (col < ki) ? f2bs(x[(size_t)node * ki + col] * dinv[node]) : (ushort)0;
}

// ---------------- W[KI,KO] fp32 -> Wt[KO,LD] bf16 (transposed, zero-padded) ----------------
__global__ void transpose_w_bf16(const float* __restrict__ W, ushort* __restrict__ Wt,
                                 int ki, int ko, int ld) {
    int i = blockIdx.x * blockDim.x + threadIdx.x;
    int total = ko * ld;
    if (i >= total) return;
    int o = i / ld, k = i % ld;
    Wt[i] = (k < ki) ? f2bs(W[(size_t)k * ko + o]) : (ushort)0;
}

// ---------------- Kxt[32][6000] fp32 -> Kbf[32][6016] bf16 (zero-padded) ----------------
__global__ void convert_k_bf16(const float* __restrict__ Kxt, ushort* __restrict__ Kbf) {
    int i = blockIdx.x * blockDim.x + threadIdx.x;
    if (i >= 32 * 6016) return;
    int o = i / 6016, k = i % 6016;
    Kbf[i] = (k < 6000) ? f2bs(Kxt[(size_t)o * 6000 + k]) : (ushort)0;
}

// ---------------- vectorized GCN aggregation on dinv-prescaled features ----------------
template <int LD>
__global__ void gcn_gather_vec(const ushort* __restrict__ h, const int* __restrict__ row_ptr,
                               const int* __restrict__ csr_src, const float* __restrict__ dinv,
                               ushort* __restrict__ agg, int n) {
    constexpr int TPN = LD / 8;
    int gid = blockIdx.x * blockDim.x + threadIdx.x;
    int node = gid / TPN, oct = gid % TPN;
    if (node >= n) return;
    float dn = dinv[node];
    int e0 = row_ptr[node], e1 = row_ptr[node + 1];
    float acc[8];
    {   // self term: h'[node]
        uint4 v = *reinterpret_cast<const uint4*>(&h[(size_t)node * LD + oct * 8]);
        unpack2(v.x, acc[0], acc[1]);
        unpack2(v.y, acc[2], acc[3]);
        unpack2(v.z, acc[4], acc[5]);
        unpack2(v.w, acc[6], acc[7]);
    }
    for (int e = e0; e < e1; ++e) {
        int s = csr_src[e];
        uint4 v = *reinterpret_cast<const uint4*>(&h[(size_t)s * LD + oct * 8]);
        float a, b;
        unpack2(v.x, a, b); acc[0] += a; acc[1] += b;
        unpack2(v.y, a, b); acc[2] += a; acc[3] += b;
        unpack2(v.z, a, b); acc[4] += a; acc[5] += b;
        unpack2(v.w, a, b); acc[6] += a; acc[7] += b;
    }
    uint4 o;
    o.x = (uint)f2bs(acc[0] * dn) | ((uint)f2bs(acc[1] * dn) << 16);
    o.y = (uint)f2bs(acc[2] * dn) | ((uint)f2bs(acc[3] * dn) << 16);
    o.z = (uint)f2bs(acc[4] * dn) | ((uint)f2bs(acc[5] * dn) << 16);
    o.w = (uint)f2bs(acc[6] * dn) | ((uint)f2bs(acc[7] * dn) << 16);
    *reinterpret_cast<uint4*>(&agg[(size_t)node * LD + oct * 8]) = o;
}

// ---------------- bf16 MFMA GEMM: C = A @ Wt^T (+bias+relu)(*rowscale), bf16 out ----------------
template <int KI, int LDA, int KO, int LDC, int NBY, bool SCALEROW>
__global__ __launch_bounds__(256) void gemm_mfma(const ushort* __restrict__ A,
                                                 const ushort* __restrict__ Bt,
                                                 const float* __restrict__ bias,
                                                 const float* __restrict__ rowscale,
                                                 ushort* __restrict__ C, int n) {
    __shared__ ushort sA[64][40];
    __shared__ ushort sB[64][40];
    const int t = threadIdx.x;
    const int row0 = (blockIdx.x / NBY) * 64;
    const int col0 = (blockIdx.x % NBY) * 64;
    const int wid = t >> 6, lane = t & 63;
    const int wr = wid >> 1, wc = wid & 1;
    const int lrow = lane & 15;
    const int kgrp = lane >> 4;
    const int srr = t >> 2;      // staging row 0..63
    const int skq = t & 3;       // staging k-octet
    f32x4 acc[2][2];
#pragma unroll
    for (int i = 0; i < 2; ++i)
#pragma unroll
        for (int j = 0; j < 2; ++j) acc[i][j] = (f32x4)0.f;

    const int nk = (KI + 31) / 32;
    for (int ks = 0; ks < nk; ++ks) {
        const int kbase = ks * 32 + skq * 8;
        {   // stage A tile (64 rows x 32 k)
            int grow = row0 + srr;
            uint4 v = {0, 0, 0, 0};
            if (grow < n && kbase < LDA)
                v = *reinterpret_cast<const uint4*>(&A[(size_t)grow * LDA + kbase]);
            *reinterpret_cast<uint4*>(&sA[srr][skq * 8]) = v;
        }
        {   // stage B tile (64 cols x 32 k)
            int gcol = col0 + srr;
            uint4 v = {0, 0, 0, 0};
            if (gcol < KO && kbase < LDA)
                v = *reinterpret_cast<const uint4*>(&Bt[(size_t)gcol * LDA + kbase]);
            *reinterpret_cast<uint4*>(&sB[srr][skq * 8]) = v;
        }
        __syncthreads();
        s16x8 a0 = *reinterpret_cast<const s16x8*>(&sA[wr * 32 + lrow][kgrp * 8]);
        s16x8 a1 = *reinterpret_cast<const s16x8*>(&sA[wr * 32 + 16 + lrow][kgrp * 8]);
        s16x8 b0 = *reinterpret_cast<const s16x8*>(&sB[wc * 32 + lrow][kgrp * 8]);
        s16x8 b1 = *reinterpret_cast<const s16x8*>(&sB[wc * 32 + 16 + lrow][kgrp * 8]);
        acc[0][0] = __builtin_amdgcn_mfma_f32_16x16x32_bf16(a0, b0, acc[0][0], 0, 0, 0);
        acc[0][1] = __builtin_amdgcn_mfma_f32_16x16x32_bf16(a0, b1, acc[0][1], 0, 0, 0);
        acc[1][0] = __builtin_amdgcn_mfma_f32_16x16x32_bf16(a1, b0, acc[1][0], 0, 0, 0);
        acc[1][1] = __builtin_amdgcn_mfma_f32_16x16x32_bf16(a1, b1, acc[1][1], 0, 0, 0);
        __syncthreads();
    }
#pragma unroll
    for (int fr = 0; fr < 2; ++fr)
#pragma unroll
        for (int fc = 0; fc < 2; ++fc)
#pragma unroll
            for (int r = 0; r < 4; ++r) {
                int row = row0 + wr * 32 + fr * 16 + kgrp * 4 + r;
                int col = col0 + wc * 32 + fc * 16 + lrow;
                if (row < n && col < LDC) {
                    float v = acc[fr][fc][r];
                    ushort o = 0;
                    if (col < KO) {
                        v = fmaxf(v + bias[col], 0.f);
                        if (SCALEROW) v *= rowscale[row];
                        o = f2bs(v);
                    }
                    C[(size_t)row * LDC + col] = o;
                }
            }
}

// ---------------- layer-3 MFMA GEMM with FUSED segment-max pool (XCD-chunked grid) ----------------
__global__ __launch_bounds__(256) void gemm_mfma_segmax(const ushort* __restrict__ A,
                                                        const ushort* __restrict__ Bt,
                                                        const float* __restrict__ bias,
                                                        const int* __restrict__ batch,
                                                        uint* __restrict__ g0u, int n) {
    constexpr int KI = 156, LDA = 160, KO = 312, NBY = 5;
    constexpr int NRG = (N_NODESC + 63) / 64;        // 1563 row-groups
    constexpr int Q = NRG / 8, R = NRG % 8;          // chunks of 196 (xcd<R) or 195
    __shared__ ushort sA[64][40];
    __shared__ ushort sB[64][40];
    __shared__ ushort sC[64][66];
    __shared__ int sbatch[64];
    const int bid = blockIdx.x;
    const int xcd = bid & 7;
    const int idx = bid >> 3;
    const int chunk = Q + (xcd < R ? 1 : 0);
    const int rgl = idx / NBY;
    if (rgl >= chunk) return;                        // uniform idle block (pre-barrier)
    const int rg = xcd * Q + min(xcd, R) + rgl;
    const int row0 = rg * 64;
    const int col0 = (idx % NBY) * 64;
    const int t = threadIdx.x;
    const int wid = t >> 6, lane = t & 63;
    const int wr = wid >> 1, wc = wid & 1;
    const int lrow = lane & 15;
    const int kgrp = lane >> 4;
    const int srr = t >> 2;
    const int skq = t & 3;
    if (t < 64) sbatch[t] = (row0 + t < n) ? batch[row0 + t] : -1;
    f32x4 acc[2][2];
#pragma unroll
    for (int i = 0; i < 2; ++i)
#pragma unroll
        for (int j = 0; j < 2; ++j) acc[i][j] = (f32x4)0.f;

    const int nk = (KI + 31) / 32;
    for (int ks = 0; ks < nk; ++ks) {
        const int kbase = ks * 32 + skq * 8;
        {
            int grow = row0 + srr;
            uint4 v = {0, 0, 0, 0};
            if (grow < n && kbase < LDA)
                v = *reinterpret_cast<const uint4*>(&A[(size_t)grow * LDA + kbase]);
            *reinterpret_cast<uint4*>(&sA[srr][skq * 8]) = v;
        }
        {
            int gcol = col0 + srr;
            uint4 v = {0, 0, 0, 0};
            if (gcol < KO && kbase < LDA)
                v = *reinterpret_cast<const uint4*>(&Bt[(size_t)gcol * LDA + kbase]);
            *reinterpret_cast<uint4*>(&sB[srr][skq * 8]) = v;
        }
        __syncthreads();
        s16x8 a0 = *reinterpret_cast<const s16x8*>(&sA[wr * 32 + lrow][kgrp * 8]);
        s16x8 a1 = *reinterpret_cast<const s16x8*>(&sA[wr * 32 + 16 + lrow][kgrp * 8]);
        s16x8 b0 = *reinterpret_cast<const s16x8*>(&sB[wc * 32 + lrow][kgrp * 8]);
        s16x8 b1 = *reinterpret_cast<const s16x8*>(&sB[wc * 32 + 16 + lrow][kgrp * 8]);
        acc[0][0] = __builtin_amdgcn_mfma_f32_16x16x32_bf16(a0, b0, acc[0][0], 0, 0, 0);
        acc[0][1] = __builtin_amdgcn_mfma_f32_16x16x32_bf16(a0, b1, acc[0][1], 0, 0, 0);
        acc[1][0] = __builtin_amdgcn_mfma_f32_16x16x32_bf16(a1, b0, acc[1][0], 0, 0, 0);
        acc[1][1] = __builtin_amdgcn_mfma_f32_16x16x32_bf16(a1, b1, acc[1][1], 0, 0, 0);
        __syncthreads();
    }
#pragma unroll
    for (int fr = 0; fr < 2; ++fr)
#pragma unroll
        for (int fc = 0; fc < 2; ++fc)
#pragma unroll
            for (int r = 0; r < 4; ++r) {
                int lr = wr * 32 + fr * 16 + kgrp * 4 + r;
                int lc = wc * 32 + fc * 16 + lrow;
                int gcol = col0 + lc;
                ushort o = 0;
                if (gcol < KO) o = f2bs(fmaxf(acc[fr][fc][r] + bias[gcol], 0.f));
                sC[lr][lc] = o;
            }
    __syncthreads();
    {
        int col = t & 63, q = t >> 6;
        int gcol = col0 + col;
        if (gcol < KO) {
            int base = q * 16;
            int cur = sbatch[base];
            float m = 0.f;
#pragma unroll 4
            for (int i = 0; i < 16; ++i) {
                int b = sbatch[base + i];
                if (b != cur) {
                    if (cur >= 0) atomicMax(&g0u[(size_t)cur * KO + gcol], __float_as_uint(m));
                    m = 0.f;
                    cur = b;
                }
                m = fmaxf(m, b2f(sC[base + i][col]));
            }
            if (cur >= 0) atomicMax(&g0u[(size_t)cur * KO + gcol], __float_as_uint(m));
        }
    }
}

// ---------------- head GEMM: K-split, 32x64 tile, fp32 partials ----------------
template <int KI, int KO, int KS>
__global__ __launch_bounds__(256) void gemm_head(const float* __restrict__ A,
                                                 const float* __restrict__ W,
                                                 float* __restrict__ partial, int n) {
    __shared__ float sA[16][34];
    __shared__ float sW[16][68];
    const int t = threadIdx.x;
    const int row0 = blockIdx.x * 32;
    const int col0 = blockIdx.y * 64;
    const int z = blockIdx.z;
    const int kbeg = z * KS;
    const int kend = min(KI, kbeg + KS);
    const int r0 = (t >> 4) * 2;   // 0..30 (even)
    const int c0 = (t & 15) * 4;   // 0..60 (quad)
    float acc[2][4] = {};
    for (int k0 = kbeg; k0 < kend; k0 += 16) {
        {   // stage A: 32 rows x 16 k
            int row = t >> 3, kk = (t & 7) * 2;
            int grow = row0 + row;
#pragma unroll
            for (int j = 0; j < 2; ++j) {
                float v = 0.f;
                if (grow < n && (k0 + kk + j) < kend) v = A[(size_t)grow * KI + k0 + kk + j];
                sA[kk + j][row] = v;
            }
        }
        {   // stage W: 16 k x 64 cols
            int kk = t >> 4, cc = (t & 15) * 4;
#pragma unroll
            for (int j = 0; j < 4; ++j) {
                float v = 0.f;
                if ((k0 + kk) < kend) v = W[(size_t)(k0 + kk) * KO + col0 + cc + j];
                sW[kk][cc + j] = v;
            }
        }
        __syncthreads();
#pragma unroll 8
        for (int k = 0; k < 16; ++k) {
            float2 a = *reinterpret_cast<const float2*>(&sA[k][r0]);
            float4 w = *reinterpret_cast<const float4*>(&sW[k][c0]);
            acc[0][0] = fmaf(a.x, w.x, acc[0][0]); acc[0][1] = fmaf(a.x, w.y, acc[0][1]);
            acc[0][2] = fmaf(a.x, w.z, acc[0][2]); acc[0][3] = fmaf(a.x, w.w, acc[0][3]);
            acc[1][0] = fmaf(a.y, w.x, acc[1][0]); acc[1][1] = fmaf(a.y, w.y, acc[1][1]);
            acc[1][2] = fmaf(a.y, w.z, acc[1][2]); acc[1][3] = fmaf(a.y, w.w, acc[1][3]);
        }
        __syncthreads();
    }
#pragma unroll
    for (int ri = 0; ri < 2; ++ri) {
        int row = row0 + r0 + ri;
        if (row >= n) continue;
        *reinterpret_cast<float4*>(&partial[((size_t)z * n + row) * KO + col0 + c0]) =
            make_float4(acc[ri][0], acc[ri][1], acc[ri][2], acc[ri][3]);
    }
}

// sum partials over splits + bias (+relu), scatter into C[row*ldc + col_off + col]
template <int NS, bool RELU>
__global__ void head_reduce(const float* __restrict__ partial, const float* __restrict__ bias,
                            float* __restrict__ C, int n, int KO, int ldc, int col_off) {
    int j = blockIdx.x * blockDim.x + threadIdx.x;
    if (j >= n * KO) return;
    int row = j / KO, col = j % KO;
    float acc = bias[col];
#pragma unroll
    for (int s = 0; s < NS; ++s) acc += partial[((size_t)s * n + row) * KO + col];
    if (RELU) acc = fmaxf(acc, 0.f);
    C[(size_t)row * ldc + col_off + col] = acc;
}

// ---------------- Conv1d as implicit GEMM via MFMA: coalesced T-region load + LDS transpose ----------------
// Per K32-step, the block needs T[b0..b0+6][i0..i0+3][0..18] (7 runs of 76 consecutive floats).
// Stage it coalesced into sT, then build the bf16 A-tile from LDS (cheap reads) instead of
// 8 scattered scalar global loads per thread.
__global__ __launch_bounds__(256) void conv_mfma(const float* __restrict__ T,
                                                 const ushort* __restrict__ Kbf,
                                                 float* __restrict__ partial) {
    __shared__ ushort sA[64][40];
    __shared__ ushort sB[32][40];
    __shared__ float sT[7][4][20];
    const int t = threadIdx.x;
    const int row0 = blockIdx.x * 64;
    const int split = blockIdx.y;
    const int kbeg = split * CONV_KCHUNK;
    const int kend = min(6000, kbeg + CONV_KCHUNK);
    const int wid = t >> 6, lane = t & 63;
    const int lrow = lane & 15, kgrp = lane >> 4;
    const int rr = t >> 2, kq = t & 3;
    const int grow = row0 + rr;                  // < 6144 always
    const int bb = grow / 12, hh = grow % 12;
    const int b0 = row0 / 12;
    const int bl = bb - b0;                      // 0..6
    f32x4 acc0 = (f32x4)0.f, acc1 = (f32x4)0.f;
    for (int k0 = kbeg; k0 < kend; k0 += 32) {
        const int i0 = k0 >> 3;
        // ---- issue B load early (written to LDS after the barrier) ----
        uint4 vb;
        if (t < 128) {
            int o = t >> 2, q2 = t & 3;
            vb = *reinterpret_cast<const uint4*>(&Kbf[(size_t)o * 6016 + k0 + q2 * 8]);
        }
        // ---- coalesced T-region load: 7 x 76 consecutive floats ----
        for (int f = t; f < 7 * 76; f += 256) {
            int fb = f / 76, fi = f - fb * 76;
            int ii = fi / 19, fh = fi - ii * 19;
            int gb = b0 + fb;
            float v = 0.f;
            if (gb < NBATCH && (i0 + ii) < 750)
                v = T[(size_t)gb * 14250 + (size_t)(i0 + ii) * 19 + fh];
            sT[fb][ii][fh] = v;
        }
        __syncthreads();
        // ---- build A-tile from LDS + write B-tile ----
        {
            int kb = k0 + kq * 8;                // multiple of 8 -> channel i0+kq, taps hh..hh+7
            ushort u[8];
#pragma unroll
            for (int j = 0; j < 8; ++j)
                u[j] = (kb + j < kend) ? f2bs(sT[bl][kq][hh + j]) : (ushort)0;
            uint4 v;
            v.x = (uint)u[0] | ((uint)u[1] << 16);
            v.y = (uint)u[2] | ((uint)u[3] << 16);
            v.z = (uint)u[4] | ((uint)u[5] << 16);
            v.w = (uint)u[6] | ((uint)u[7] << 16);
            *reinterpret_cast<uint4*>(&sA[rr][kq * 8]) = v;
        }
        if (t < 128) {
            int o = t >> 2, q2 = t & 3;
            *reinterpret_cast<uint4*>(&sB[o][q2 * 8]) = vb;
        }
        __syncthreads();
        s16x8 a0 = *reinterpret_cast<const s16x8*>(&sA[wid * 16 + lrow][kgrp * 8]);
        s16x8 b0v = *reinterpret_cast<const s16x8*>(&sB[lrow][kgrp * 8]);
        s16x8 b1v = *reinterpret_cast<const s16x8*>(&sB[16 + lrow][kgrp * 8]);
        acc0 = __builtin_amdgcn_mfma_f32_16x16x32_bf16(a0, b0v, acc0, 0, 0, 0);
        acc1 = __builtin_amdgcn_mfma_f32_16x16x32_bf16(a0, b1v, acc1, 0, 0, 0);
        __syncthreads();
    }
#pragma unroll
    for (int r = 0; r < 4; ++r) {
        int row = row0 + wid * 16 + kgrp * 4 + r;   // C/D: row=(lane>>4)*4+reg, col=lane&15
        int b = row / 12, h = row % 12;
        partial[(((size_t)split * NBATCH + b) * 32 + lrow) * 12 + h] = acc0[r];
        partial[(((size_t)split * NBATCH + b) * 32 + (16 + lrow)) * 12 + h] = acc1[r];
    }
}

__global__ void conv_reduce(const float* __restrict__ partial, const float* __restrict__ bxt,
                            float* __restrict__ convb) {
    int j = blockIdx.x * blockDim.x + threadIdx.x;
    if (j >= NBATCH * 384) return;
    int b = j / 384, rem = j % 384;
    int o = rem / 12, h = rem % 12;
    float acc = bxt[o];
#pragma unroll
    for (int s = 0; s < CONV_KSPLIT; ++s)
        acc += partial[(((size_t)s * NBATCH + b) * 32 + o) * 12 + h];
    convb[j] = acc;
}

// ---------------- final [512,512] @ [512,1] ----------------
__global__ void final_out(const float* __restrict__ f2, const float* __restrict__ Wo,
                          const float* __restrict__ bo, float* __restrict__ out) {
    int row = blockIdx.x * (blockDim.x / 64) + (threadIdx.x / 64);
    int lane = threadIdx.x & 63;
    if (row >= NBATCH) return;
    float acc = 0.f;
    for (int k = lane; k < 512; k += 64) acc = fmaf(f2[(size_t)row * 512 + k], Wo[k], acc);
#pragma unroll
    for (int off = 32; off > 0; off >>= 1) acc += __shfl_down(acc, off);
    if (lane == 0) out[row] = acc + bo[0];
}

extern "C" void kernel_launch(void* const* d_in, const int* in_sizes, int n_in,
                              void* d_out, int out_size, void* d_ws, size_t ws_size,
                              hipStream_t stream) {
    (void)in_sizes; (void)n_in; (void)out_size; (void)ws_size;
    const float* x     = (const float*)d_in[0];
    const int*   ei    = (const int*)d_in[1];
    const int*   batch = (const int*)d_in[2];
    const float* T     = (const float*)d_in[3];
    const float* W1 = (const float*)d_in[4];   const float* b1 = (const float*)d_in[5];
    const float* W2 = (const float*)d_in[6];   const float* b2 = (const float*)d_in[7];
    const float* W3 = (const float*)d_in[8];   const float* b3 = (const float*)d_in[9];
    const float* Wg1 = (const float*)d_in[10]; const float* bg1 = (const float*)d_in[11];
    const float* Wg2 = (const float*)d_in[12]; const float* bg2 = (const float*)d_in[13];
    const float* Kxt = (const float*)d_in[14]; const float* bxt = (const float*)d_in[15];
    const float* Wxt = (const float*)d_in[16]; const float* bxt2 = (const float*)d_in[17];
    const float* Wf1 = (const float*)d_in[18]; const float* bf1 = (const float*)d_in[19];
    const float* Wf2 = (const float*)d_in[20]; const float* bf2 = (const float*)d_in[21];
    const float* Wo = (const float*)d_in[22];  const float* bo = (const float*)d_in[23];
    const int* src = ei;
    const int* dst = ei + N_EDGESC;

    char* ws = (char*)d_ws;
    size_t off = 0;
    auto alloc = [&](size_t bytes) -> void* {
        void* p = ws + off;
        off += (bytes + 255) & ~(size_t)255;
        return p;
    };
    int*   deg      = (int*)alloc((size_t)N_NODESC * 4);
    float* dinv     = (float*)alloc((size_t)N_NODESC * 4);
    int*   row_ptr  = (int*)alloc((size_t)(N_NODESC + 1) * 4);
    int*   fillc    = (int*)alloc((size_t)N_NODESC * 4);
    int*   csr_src  = (int*)alloc((size_t)N_EDGESC * 4);
    int*   csums    = (int*)alloc((size_t)4096 * 4);
    float* g0       = (float*)alloc((size_t)NBATCH * 312 * 4);
    float* g1       = (float*)alloc((size_t)NBATCH * 1024 * 4);
    float* convb    = (float*)alloc((size_t)NBATCH * 384 * 4);
    float* xc       = (float*)alloc((size_t)NBATCH * 256 * 4);
    float* f1       = (float*)alloc((size_t)NBATCH * 1024 * 4);
    float* f2       = (float*)alloc((size_t)NBATCH * 512 * 4);
    float* cpart    = (float*)alloc((size_t)CONV_KSPLIT * NBATCH * 32 * 12 * 4);
    float* hpart    = (float*)alloc((size_t)4 * NBATCH * 1024 * 4);   // 8MB: max NS*n*KO
    ushort* xbf     = (ushort*)alloc((size_t)N_NODESC * 80 * 2);   // x' (80) -> later h1' (80)
    ushort* aggbuf  = (ushort*)alloc((size_t)N_NODESC * 160 * 2);  // agg1/2 (80), agg3 (160)
    ushort* hbuf    = (ushort*)alloc((size_t)N_NODESC * 160 * 2);  // h2' (160)
    ushort* Wt1     = (ushort*)alloc((size_t)78 * 80 * 2);
    ushort* Wt2     = (ushort*)alloc((size_t)156 * 80 * 2);
    ushort* Wt3     = (ushort*)alloc((size_t)312 * 160 * 2);
    ushort* Kbf     = (ushort*)alloc((size_t)32 * 6016 * 2);
    float* out      = (float*)d_out;

    const int TPB = 256;

    // ---- graph structure ----
    zero_ints<<<divup(N_NODESC, TPB), TPB, 0, stream>>>(deg, N_NODESC);
    count_deg<<<divup(N_EDGESC, TPB), TPB, 0, stream>>>(dst, deg, N_EDGESC);
    compute_dinv<<<divup(N_NODESC, TPB), TPB, 0, stream>>>(deg, dinv, N_NODESC);
    int nchunks = divup(N_NODESC, SCAN_CHUNK);
    scan_chunks<<<nchunks, 256, 0, stream>>>(deg, row_ptr, csums, N_NODESC);
    scan_sums<<<1, 64, 0, stream>>>(csums, nchunks);
    finalize_rowptr<<<divup(N_NODESC, TPB), TPB, 0, stream>>>(row_ptr, csums, fillc, N_NODESC, N_EDGESC);
    fill_csr<<<divup(N_EDGESC, TPB), TPB, 0, stream>>>(src, dst, fillc, csr_src, N_EDGESC);

    // ---- bf16 conversions (x folded with dinv) ----
    convert_x_bf16<<<divup(N_NODESC * 80, TPB), TPB, 0, stream>>>(x, dinv, xbf, N_NODESC, 78, 80);
    transpose_w_bf16<<<divup(78 * 80, TPB), TPB, 0, stream>>>(W1, Wt1, 78, 78, 80);
    transpose_w_bf16<<<divup(156 * 80, TPB), TPB, 0, stream>>>(W2, Wt2, 78, 156, 80);
    transpose_w_bf16<<<divup(312 * 160, TPB), TPB, 0, stream>>>(W3, Wt3, 156, 312, 160);
    convert_k_bf16<<<divup(32 * 6016, TPB), TPB, 0, stream>>>(Kxt, Kbf);

    // ---- GCN layer 1: agg(x') -> gemm(+bias+relu, *dinv) -> h1' (LD 80) ----
    gcn_gather_vec<80><<<divup(N_NODESC * 10, TPB), TPB, 0, stream>>>(
        xbf, row_ptr, csr_src, dinv, aggbuf, N_NODESC);
    gemm_mfma<78, 80, 78, 80, 2, true><<<divup(N_NODESC, 64) * 2, 256, 0, stream>>>(
        aggbuf, Wt1, b1, dinv, xbf, N_NODESC);   // h1' overwrites xbf

    // ---- GCN layer 2: agg(h1') -> gemm(*dinv) -> h2' (LD 160) ----
    gcn_gather_vec<80><<<divup(N_NODESC * 10, TPB), TPB, 0, stream>>>(
        xbf, row_ptr, csr_src, dinv, aggbuf, N_NODESC);
    gemm_mfma<78, 80, 156, 160, 3, true><<<divup(N_NODESC, 64) * 3, 256, 0, stream>>>(
        aggbuf, Wt2, b2, dinv, hbuf, N_NODESC);

    // ---- GCN layer 3: agg(h2') -> gemm + FUSED segment-max (XCD-chunked grid) ----
    gcn_gather_vec<160><<<divup(N_NODESC * 20, TPB), TPB, 0, stream>>>(
        hbuf, row_ptr, csr_src, dinv, aggbuf, N_NODESC);
    zero_ints<<<divup(NBATCH * 312, TPB), TPB, 0, stream>>>((int*)g0, NBATCH * 312);
    gemm_mfma_segmax<<<8 * 196 * 5, 256, 0, stream>>>(
        aggbuf, Wt3, b3, batch, (uint*)g0, N_NODESC);

    // ---- graph head: g1 = relu(g0 @ Wg1 + bg1) — 3 K-splits, 768 blocks ----
    gemm_head<312, 1024, 112><<<dim3(16, 16, 3), 256, 0, stream>>>(g0, Wg1, hpart, NBATCH);
    head_reduce<3, true><<<divup(NBATCH * 1024, TPB), TPB, 0, stream>>>(
        hpart, bg1, g1, NBATCH, 1024, 1024, 0);
    // xc[:, :128] = g1 @ Wg2 + bg2 — 16 K-splits, 512 blocks
    gemm_head<1024, 128, 64><<<dim3(16, 2, 16), 256, 0, stream>>>(g1, Wg2, hpart, NBATCH);
    head_reduce<16, false><<<divup(NBATCH * 128, TPB), TPB, 0, stream>>>(
        hpart, bg2, xc, NBATCH, 128, 256, 0);

    // ---- protein branch: implicit-GEMM conv via MFMA (coalesced region + LDS transpose) ----
    conv_mfma<<<dim3(6144 / 64, CONV_KSPLIT), 256, 0, stream>>>(T, Kbf, cpart);
    conv_reduce<<<divup(NBATCH * 384, TPB), TPB, 0, stream>>>(cpart, bxt, convb);
    // xc[:, 128:] = convb @ Wxt + bxt2 — 16 K-splits, 512 blocks
    gemm_head<384, 128, 24><<<dim3(16, 2, 16), 256, 0, stream>>>(convb, Wxt, hpart, NBATCH);
    head_reduce<16, false><<<divup(NBATCH * 128, TPB), TPB, 0, stream>>>(
        hpart, bxt2, xc, NBATCH, 128, 256, 128);

    // ---- fusion MLP: f1 — 4 K-splits, 1024 blocks; f2 — 8 K-splits, 1024 blocks ----
    gemm_head<256, 1024, 64><<<dim3(16, 16, 4), 256, 0, stream>>>(xc, Wf1, hpart, NBATCH);
    head_reduce<4, true><<<divup(NBATCH * 1024, TPB), TPB, 0, stream>>>(
        hpart, bf1, f1, NBATCH, 1024, 1024, 0);
    gemm_head<1024, 512, 128><<<dim3(16, 8, 8), 256, 0, stream>>>(f1, Wf2, hpart, NBATCH);
    head_reduce<8, true><<<divup(NBATCH * 512, TPB), TPB, 0, stream>>>(
        hpart, bf2, f2, NBATCH, 512, 512, 0);
    final_out<<<divup(NBATCH, 4), 256, 0, stream>>>(f2, Wo, bo, out);
}

// Round 19
// 374.223 us; speedup vs baseline: 1.0436x; 1.0188x over previous
//
#include <hip/hip_runtime.h>
#include <hip/hip_bf16.h>
#include <cstddef>
#include <cstdint>

#define N_NODESC 100000
#define N_EDGESC 500000
#define NBATCH   512
#define SCAN_CHUNK 1024
#define CONV_KSPLIT 16
#define CONV_KCHUNK 384    // multiple of 32 -> k-octets stay channel-aligned; last split ragged (240)

static inline int divup(int a, int b) { return (a + b - 1) / b; }

typedef __hip_bfloat16 bf16;
typedef short s16x8 __attribute__((ext_vector_type(8)));
typedef float f32x4 __attribute__((ext_vector_type(4)));

__device__ inline float b2f(ushort u) {
    union { uint i; float f; } c; c.i = (uint)u << 16; return c.f;
}
__device__ inline ushort f2bs(float v) {
    bf16 b = __float2bfloat16(v);
    return *reinterpret_cast<ushort*>(&b);
}
__device__ inline void unpack2(uint u, float& a, float& b) {
    union { uint i; float f; } lo, hi;
    lo.i = u << 16; hi.i = u & 0xffff0000u;
    a = lo.f; b = hi.f;
}

// ---------------- zero two int ranges (deg + g0) ----------------
__global__ void zero2(int* __restrict__ p1, int n1, int* __restrict__ p2, int n2) {
    int i = blockIdx.x * blockDim.x + threadIdx.x;
    if (i < n1) p1[i] = 0;
    if (i < n2) p2[i] = 0;
}

// ---------------- degree ----------------
__global__ void count_deg(const int* __restrict__ dst, int* __restrict__ deg, int e) {
    int i = blockIdx.x * blockDim.x + threadIdx.x;
    if (i < e) atomicAdd(&deg[dst[i]], 1);
}

// ---------------- exclusive scan (3-phase) ----------------
__global__ void scan_chunks(const int* __restrict__ deg, int* __restrict__ out,
                            int* __restrict__ sums, int n) {
    __shared__ int sdata[256];
    int t = threadIdx.x;
    int base = blockIdx.x * SCAN_CHUNK;
    int v[4];
    int s = 0;
#pragma unroll
    for (int j = 0; j < 4; ++j) {
        int idx = base + t * 4 + j;
        v[j] = s;
        int d = (idx < n) ? deg[idx] : 0;
        s += d;
    }
    int x = s;
    sdata[t] = x;
    __syncthreads();
    for (int off = 1; off < 256; off <<= 1) {
        int y = (t >= off) ? sdata[t - off] : 0;
        __syncthreads();
        x += y;
        sdata[t] = x;
        __syncthreads();
    }
    int thread_excl = x - s;
    if (t == 255) sums[blockIdx.x] = x;
#pragma unroll
    for (int j = 0; j < 4; ++j) {
        int idx = base + t * 4 + j;
        if (idx < n) out[idx] = thread_excl + v[j];
    }
}

__global__ void scan_sums(int* sums, int nchunks) {
    if (threadIdx.x == 0 && blockIdx.x == 0) {
        int acc = 0;
        for (int i = 0; i < nchunks; ++i) { int v = sums[i]; sums[i] = acc; acc += v; }
    }
}

__global__ void finalize_rowptr(int* __restrict__ row_ptr, const int* __restrict__ sums,
                                int* __restrict__ fill, int n, int e) {
    int i = blockIdx.x * blockDim.x + threadIdx.x;
    if (i < n) {
        int v = row_ptr[i] + sums[i / SCAN_CHUNK];
        row_ptr[i] = v;
        fill[i] = v;
    }
    if (i == 0) row_ptr[n] = e;
}

__global__ void fill_csr(const int* __restrict__ src, const int* __restrict__ dst,
                         int* __restrict__ fill, int* __restrict__ csr_src, int e) {
    int i = blockIdx.x * blockDim.x + threadIdx.x;
    if (i < e) {
        int d = dst[i];
        int pos = atomicAdd(&fill[d], 1);
        csr_src[pos] = src[i];
    }
}

// ---------------- x -> bf16 scaled by dinv; also materializes dinv (col 0) ----------------
__global__ void convert_x_dinv(const float* __restrict__ x, const int* __restrict__ deg,
                               float* __restrict__ dinv, ushort* __restrict__ xbf,
                               int n, int ki, int ld) {
    int i = blockIdx.x * blockDim.x + threadIdx.x;
    int total = n * ld;
    if (i >= total) return;
    int node = i / ld, col = i % ld;
    float dn = 1.0f / sqrtf((float)deg[node] + 1.0f);   // identical expr to old compute_dinv
    if (col == 0) dinv[node] = dn;
    xbf[i] = (col < ki) ? f2bs(x[(size_t)node * ki + col] * dn) : (ushort)0;
}

// ---------------- all weight conversions in one kernel (range dispatch) ----------------
// ranges: [0,6240)       Wt1: 78x80  from W1(78x78)   (transpose, pad)
//         [6240,18720)   Wt2: 156x80 from W2(78x156)
//         [18720,68640)  Wt3: 312x160 from W3(156x312)
//         [68640,261152) Kbf: 32x6016 from Kxt(32x6000) (no transpose, pad)
__global__ void convert_weights(const float* __restrict__ W1, const float* __restrict__ W2,
                                const float* __restrict__ W3, const float* __restrict__ Kxt,
                                ushort* __restrict__ Wt1, ushort* __restrict__ Wt2,
                                ushort* __restrict__ Wt3, ushort* __restrict__ Kbf) {
    int i = blockIdx.x * blockDim.x + threadIdx.x;
    if (i < 6240) {
        int o = i / 80, k = i % 80;
        Wt1[i] = (k < 78) ? f2bs(W1[(size_t)k * 78 + o]) : (ushort)0;
    } else if (i < 18720) {
        int j = i - 6240;
        int o = j / 80, k = j % 80;
        Wt2[j] = (k < 78) ? f2bs(W2[(size_t)k * 156 + o]) : (ushort)0;
    } else if (i < 68640) {
        int j = i - 18720;
        int o = j / 160, k = j % 160;
        Wt3[j] = (k < 156) ? f2bs(W3[(size_t)k * 312 + o]) : (ushort)0;
    } else if (i < 261152) {
        int j = i - 68640;
        int o = j / 6016, k = j % 6016;
        Kbf[j] = (k < 6000) ? f2bs(Kxt[(size_t)o * 6000 + k]) : (ushort)0;
    }
}

// ---------------- vectorized GCN aggregation on dinv-prescaled features ----------------
template <int LD>
__global__ void gcn_gather_vec(const ushort* __restrict__ h, const int* __restrict__ row_ptr,
                               const int* __restrict__ csr_src, const float* __restrict__ dinv,
                               ushort* __restrict__ agg, int n) {
    constexpr int TPN = LD / 8;
    int gid = blockIdx.x * blockDim.x + threadIdx.x;
    int node = gid / TPN, oct = gid % TPN;
    if (node >= n) return;
    float dn = dinv[node];
    int e0 = row_ptr[node], e1 = row_ptr[node + 1];
    float acc[8];
    {   // self term: h'[node]
        uint4 v = *reinterpret_cast<const uint4*>(&h[(size_t)node * LD + oct * 8]);
        unpack2(v.x, acc[0], acc[1]);
        unpack2(v.y, acc[2], acc[3]);
        unpack2(v.z, acc[4], acc[5]);
        unpack2(v.w, acc[6], acc[7]);
    }
    for (int e = e0; e < e1; ++e) {
        int s = csr_src[e];
        uint4 v = *reinterpret_cast<const uint4*>(&h[(size_t)s * LD + oct * 8]);
        float a, b;
        unpack2(v.x, a, b); acc[0] += a; acc[1] += b;
        unpack2(v.y, a, b); acc[2] += a; acc[3] += b;
        unpack2(v.z, a, b); acc[4] += a; acc[5] += b;
        unpack2(v.w, a, b); acc[6] += a; acc[7] += b;
    }
    uint4 o;
    o.x = (uint)f2bs(acc[0] * dn) | ((uint)f2bs(acc[1] * dn) << 16);
    o.y = (uint)f2bs(acc[2] * dn) | ((uint)f2bs(acc[3] * dn) << 16);
    o.z = (uint)f2bs(acc[4] * dn) | ((uint)f2bs(acc[5] * dn) << 16);
    o.w = (uint)f2bs(acc[6] * dn) | ((uint)f2bs(acc[7] * dn) << 16);
    *reinterpret_cast<uint4*>(&agg[(size_t)node * LD + oct * 8]) = o;
}

// ---------------- bf16 MFMA GEMM: C = A @ Wt^T (+bias+relu)(*rowscale), bf16 out ----------------
template <int KI, int LDA, int KO, int LDC, int NBY, bool SCALEROW>
__global__ __launch_bounds__(256) void gemm_mfma(const ushort* __restrict__ A,
                                                 const ushort* __restrict__ Bt,
                                                 const float* __restrict__ bias,
                                                 const float* __restrict__ rowscale,
                                                 ushort* __restrict__ C, int n) {
    __shared__ ushort sA[64][40];
    __shared__ ushort sB[64][40];
    const int t = threadIdx.x;
    const int row0 = (blockIdx.x / NBY) * 64;
    const int col0 = (blockIdx.x % NBY) * 64;
    const int wid = t >> 6, lane = t & 63;
    const int wr = wid >> 1, wc = wid & 1;
    const int lrow = lane & 15;
    const int kgrp = lane >> 4;
    const int srr = t >> 2;      // staging row 0..63
    const int skq = t & 3;       // staging k-octet
    f32x4 acc[2][2];
#pragma unroll
    for (int i = 0; i < 2; ++i)
#pragma unroll
        for (int j = 0; j < 2; ++j) acc[i][j] = (f32x4)0.f;

    const int nk = (KI + 31) / 32;
    for (int ks = 0; ks < nk; ++ks) {
        const int kbase = ks * 32 + skq * 8;
        {   // stage A tile (64 rows x 32 k)
            int grow = row0 + srr;
            uint4 v = {0, 0, 0, 0};
            if (grow < n && kbase < LDA)
                v = *reinterpret_cast<const uint4*>(&A[(size_t)grow * LDA + kbase]);
            *reinterpret_cast<uint4*>(&sA[srr][skq * 8]) = v;
        }
        {   // stage B tile (64 cols x 32 k)
            int gcol = col0 + srr;
            uint4 v = {0, 0, 0, 0};
            if (gcol < KO && kbase < LDA)
                v = *reinterpret_cast<const uint4*>(&Bt[(size_t)gcol * LDA + kbase]);
            *reinterpret_cast<uint4*>(&sB[srr][skq * 8]) = v;
        }
        __syncthreads();
        s16x8 a0 = *reinterpret_cast<const s16x8*>(&sA[wr * 32 + lrow][kgrp * 8]);
        s16x8 a1 = *reinterpret_cast<const s16x8*>(&sA[wr * 32 + 16 + lrow][kgrp * 8]);
        s16x8 b0 = *reinterpret_cast<const s16x8*>(&sB[wc * 32 + lrow][kgrp * 8]);
        s16x8 b1 = *reinterpret_cast<const s16x8*>(&sB[wc * 32 + 16 + lrow][kgrp * 8]);
        acc[0][0] = __builtin_amdgcn_mfma_f32_16x16x32_bf16(a0, b0, acc[0][0], 0, 0, 0);
        acc[0][1] = __builtin_amdgcn_mfma_f32_16x16x32_bf16(a0, b1, acc[0][1], 0, 0, 0);
        acc[1][0] = __builtin_amdgcn_mfma_f32_16x16x32_bf16(a1, b0, acc[1][0], 0, 0, 0);
        acc[1][1] = __builtin_amdgcn_mfma_f32_16x16x32_bf16(a1, b1, acc[1][1], 0, 0, 0);
        __syncthreads();
    }
#pragma unroll
    for (int fr = 0; fr < 2; ++fr)
#pragma unroll
        for (int fc = 0; fc < 2; ++fc)
#pragma unroll
            for (int r = 0; r < 4; ++r) {
                int row = row0 + wr * 32 + fr * 16 + kgrp * 4 + r;
                int col = col0 + wc * 32 + fc * 16 + lrow;
                if (row < n && col < LDC) {
                    float v = acc[fr][fc][r];
                    ushort o = 0;
                    if (col < KO) {
                        v = fmaxf(v + bias[col], 0.f);
                        if (SCALEROW) v *= rowscale[row];
                        o = f2bs(v);
                    }
                    C[(size_t)row * LDC + col] = o;
                }
            }
}

// ---------------- layer-3 MFMA GEMM with FUSED segment-max pool (XCD-chunked grid) ----------------
__global__ __launch_bounds__(256) void gemm_mfma_segmax(const ushort* __restrict__ A,
                                                        const ushort* __restrict__ Bt,
                                                        const float* __restrict__ bias,
                                                        const int* __restrict__ batch,
                                                        uint* __restrict__ g0u, int n) {
    constexpr int KI = 156, LDA = 160, KO = 312, NBY = 5;
    constexpr int NRG = (N_NODESC + 63) / 64;        // 1563 row-groups
    constexpr int Q = NRG / 8, R = NRG % 8;          // chunks of 196 (xcd<R) or 195
    __shared__ ushort sA[64][40];
    __shared__ ushort sB[64][40];
    __shared__ ushort sC[64][66];
    __shared__ int sbatch[64];
    const int bid = blockIdx.x;
    const int xcd = bid & 7;
    const int idx = bid >> 3;
    const int chunk = Q + (xcd < R ? 1 : 0);
    const int rgl = idx / NBY;
    if (rgl >= chunk) return;                        // uniform idle block (pre-barrier)
    const int rg = xcd * Q + min(xcd, R) + rgl;
    const int row0 = rg * 64;
    const int col0 = (idx % NBY) * 64;
    const int t = threadIdx.x;
    const int wid = t >> 6, lane = t & 63;
    const int wr = wid >> 1, wc = wid & 1;
    const int lrow = lane & 15;
    const int kgrp = lane >> 4;
    const int srr = t >> 2;
    const int skq = t & 3;
    if (t < 64) sbatch[t] = (row0 + t < n) ? batch[row0 + t] : -1;
    f32x4 acc[2][2];
#pragma unroll
    for (int i = 0; i < 2; ++i)
#pragma unroll
        for (int j = 0; j < 2; ++j) acc[i][j] = (f32x4)0.f;

    const int nk = (KI + 31) / 32;
    for (int ks = 0; ks < nk; ++ks) {
        const int kbase = ks * 32 + skq * 8;
        {
            int grow = row0 + srr;
            uint4 v = {0, 0, 0, 0};
            if (grow < n && kbase < LDA)
                v = *reinterpret_cast<const uint4*>(&A[(size_t)grow * LDA + kbase]);
            *reinterpret_cast<uint4*>(&sA[srr][skq * 8]) = v;
        }
        {
            int gcol = col0 + srr;
            uint4 v = {0, 0, 0, 0};
            if (gcol < KO && kbase < LDA)
                v = *reinterpret_cast<const uint4*>(&Bt[(size_t)gcol * LDA + kbase]);
            *reinterpret_cast<uint4*>(&sB[srr][skq * 8]) = v;
        }
        __syncthreads();
        s16x8 a0 = *reinterpret_cast<const s16x8*>(&sA[wr * 32 + lrow][kgrp * 8]);
        s16x8 a1 = *reinterpret_cast<const s16x8*>(&sA[wr * 32 + 16 + lrow][kgrp * 8]);
        s16x8 b0 = *reinterpret_cast<const s16x8*>(&sB[wc * 32 + lrow][kgrp * 8]);
        s16x8 b1 = *reinterpret_cast<const s16x8*>(&sB[wc * 32 + 16 + lrow][kgrp * 8]);
        acc[0][0] = __builtin_amdgcn_mfma_f32_16x16x32_bf16(a0, b0, acc[0][0], 0, 0, 0);
        acc[0][1] = __builtin_amdgcn_mfma_f32_16x16x32_bf16(a0, b1, acc[0][1], 0, 0, 0);
        acc[1][0] = __builtin_amdgcn_mfma_f32_16x16x32_bf16(a1, b0, acc[1][0], 0, 0, 0);
        acc[1][1] = __builtin_amdgcn_mfma_f32_16x16x32_bf16(a1, b1, acc[1][1], 0, 0, 0);
        __syncthreads();
    }
#pragma unroll
    for (int fr = 0; fr < 2; ++fr)
#pragma unroll
        for (int fc = 0; fc < 2; ++fc)
#pragma unroll
            for (int r = 0; r < 4; ++r) {
                int lr = wr * 32 + fr * 16 + kgrp * 4 + r;
                int lc = wc * 32 + fc * 16 + lrow;
                int gcol = col0 + lc;
                ushort o = 0;
                if (gcol < KO) o = f2bs(fmaxf(acc[fr][fc][r] + bias[gcol], 0.f));
                sC[lr][lc] = o;
            }
    __syncthreads();
    {
        int col = t & 63, q = t >> 6;
        int gcol = col0 + col;
        if (gcol < KO) {
            int base = q * 16;
            int cur = sbatch[base];
            float m = 0.f;
#pragma unroll 4
            for (int i = 0; i < 16; ++i) {
                int b = sbatch[base + i];
                if (b != cur) {
                    if (cur >= 0) atomicMax(&g0u[(size_t)cur * KO + gcol], __float_as_uint(m));
                    m = 0.f;
                    cur = b;
                }
                m = fmaxf(m, b2f(sC[base + i][col]));
            }
            if (cur >= 0) atomicMax(&g0u[(size_t)cur * KO + gcol], __float_as_uint(m));
        }
    }
}

// ---------------- head GEMM: K-split, 32x64 tile, fp32 partials ----------------
template <int KI, int KO, int KS>
__global__ __launch_bounds__(256) void gemm_head(const float* __restrict__ A,
                                                 const float* __restrict__ W,
                                                 float* __restrict__ partial, int n) {
    __shared__ float sA[16][34];
    __shared__ float sW[16][68];
    const int t = threadIdx.x;
    const int row0 = blockIdx.x * 32;
    const int col0 = blockIdx.y * 64;
    const int z = blockIdx.z;
    const int kbeg = z * KS;
    const int kend = min(KI, kbeg + KS);
    const int r0 = (t >> 4) * 2;   // 0..30 (even)
    const int c0 = (t & 15) * 4;   // 0..60 (quad)
    float acc[2][4] = {};
    for (int k0 = kbeg; k0 < kend; k0 += 16) {
        {   // stage A: 32 rows x 16 k
            int row = t >> 3, kk = (t & 7) * 2;
            int grow = row0 + row;
#pragma unroll
            for (int j = 0; j < 2; ++j) {
                float v = 0.f;
                if (grow < n && (k0 + kk + j) < kend) v = A[(size_t)grow * KI + k0 + kk + j];
                sA[kk + j][row] = v;
            }
        }
        {   // stage W: 16 k x 64 cols
            int kk = t >> 4, cc = (t & 15) * 4;
#pragma unroll
            for (int j = 0; j < 4; ++j) {
                float v = 0.f;
                if ((k0 + kk) < kend) v = W[(size_t)(k0 + kk) * KO + col0 + cc + j];
                sW[kk][cc + j] = v;
            }
        }
        __syncthreads();
#pragma unroll 8
        for (int k = 0; k < 16; ++k) {
            float2 a = *reinterpret_cast<const float2*>(&sA[k][r0]);
            float4 w = *reinterpret_cast<const float4*>(&sW[k][c0]);
            acc[0][0] = fmaf(a.x, w.x, acc[0][0]); acc[0][1] = fmaf(a.x, w.y, acc[0][1]);
            acc[0][2] = fmaf(a.x, w.z, acc[0][2]); acc[0][3] = fmaf(a.x, w.w, acc[0][3]);
            acc[1][0] = fmaf(a.y, w.x, acc[1][0]); acc[1][1] = fmaf(a.y, w.y, acc[1][1]);
            acc[1][2] = fmaf(a.y, w.z, acc[1][2]); acc[1][3] = fmaf(a.y, w.w, acc[1][3]);
        }
        __syncthreads();
    }
#pragma unroll
    for (int ri = 0; ri < 2; ++ri) {
        int row = row0 + r0 + ri;
        if (row >= n) continue;
        *reinterpret_cast<float4*>(&partial[((size_t)z * n + row) * KO + col0 + c0]) =
            make_float4(acc[ri][0], acc[ri][1], acc[ri][2], acc[ri][3]);
    }
}

// sum partials over splits + bias (+relu), scatter into C[row*ldc + col_off + col]
template <int NS, bool RELU>
__global__ void head_reduce(const float* __restrict__ partial, const float* __restrict__ bias,
                            float* __restrict__ C, int n, int KO, int ldc, int col_off) {
    int j = blockIdx.x * blockDim.x + threadIdx.x;
    if (j >= n * KO) return;
    int row = j / KO, col = j % KO;
    float acc = bias[col];
#pragma unroll
    for (int s = 0; s < NS; ++s) acc += partial[((size_t)s * n + row) * KO + col];
    if (RELU) acc = fmaxf(acc, 0.f);
    C[(size_t)row * ldc + col_off + col] = acc;
}

// ---------------- Conv1d as implicit GEMM via MFMA: coalesced T-region load + LDS transpose ----------------
__global__ __launch_bounds__(256) void conv_mfma(const float* __restrict__ T,
                                                 const ushort* __restrict__ Kbf,
                                                 float* __restrict__ partial) {
    __shared__ ushort sA[64][40];
    __shared__ ushort sB[32][40];
    __shared__ float sT[7][4][20];
    const int t = threadIdx.x;
    const int row0 = blockIdx.x * 64;
    const int split = blockIdx.y;
    const int kbeg = split * CONV_KCHUNK;
    const int kend = min(6000, kbeg + CONV_KCHUNK);
    const int wid = t >> 6, lane = t & 63;
    const int lrow = lane & 15, kgrp = lane >> 4;
    const int rr = t >> 2, kq = t & 3;
    const int grow = row0 + rr;                  // < 6144 always
    const int bb = grow / 12, hh = grow % 12;
    const int b0 = row0 / 12;
    const int bl = bb - b0;                      // 0..6
    f32x4 acc0 = (f32x4)0.f, acc1 = (f32x4)0.f;
    for (int k0 = kbeg; k0 < kend; k0 += 32) {
        const int i0 = k0 >> 3;
        uint4 vb;
        if (t < 128) {
            int o = t >> 2, q2 = t & 3;
            vb = *reinterpret_cast<const uint4*>(&Kbf[(size_t)o * 6016 + k0 + q2 * 8]);
        }
        for (int f = t; f < 7 * 76; f += 256) {
            int fb = f / 76, fi = f - fb * 76;
            int ii = fi / 19, fh = fi - ii * 19;
            int gb = b0 + fb;
            float v = 0.f;
            if (gb < NBATCH && (i0 + ii) < 750)
                v = T[(size_t)gb * 14250 + (size_t)(i0 + ii) * 19 + fh];
            sT[fb][ii][fh] = v;
        }
        __syncthreads();
        {
            int kb = k0 + kq * 8;
            ushort u[8];
#pragma unroll
            for (int j = 0; j < 8; ++j)
                u[j] = (kb + j < kend) ? f2bs(sT[bl][kq][hh + j]) : (ushort)0;
            uint4 v;
            v.x = (uint)u[0] | ((uint)u[1] << 16);
            v.y = (uint)u[2] | ((uint)u[3] << 16);
            v.z = (uint)u[4] | ((uint)u[5] << 16);
            v.w = (uint)u[6] | ((uint)u[7] << 16);
            *reinterpret_cast<uint4*>(&sA[rr][kq * 8]) = v;
        }
        if (t < 128) {
            int o = t >> 2, q2 = t & 3;
            *reinterpret_cast<uint4*>(&sB[o][q2 * 8]) = vb;
        }
        __syncthreads();
        s16x8 a0 = *reinterpret_cast<const s16x8*>(&sA[wid * 16 + lrow][kgrp * 8]);
        s16x8 b0v = *reinterpret_cast<const s16x8*>(&sB[lrow][kgrp * 8]);
        s16x8 b1v = *reinterpret_cast<const s16x8*>(&sB[16 + lrow][kgrp * 8]);
        acc0 = __builtin_amdgcn_mfma_f32_16x16x32_bf16(a0, b0v, acc0, 0, 0, 0);
        acc1 = __builtin_amdgcn_mfma_f32_16x16x32_bf16(a0, b1v, acc1, 0, 0, 0);
        __syncthreads();
    }
#pragma unroll
    for (int r = 0; r < 4; ++r) {
        int row = row0 + wid * 16 + kgrp * 4 + r;   // C/D: row=(lane>>4)*4+reg, col=lane&15
        int b = row / 12, h = row % 12;
        partial[(((size_t)split * NBATCH + b) * 32 + lrow) * 12 + h] = acc0[r];
        partial[(((size_t)split * NBATCH + b) * 32 + (16 + lrow)) * 12 + h] = acc1[r];
    }
}

__global__ void conv_reduce(const float* __restrict__ partial, const float* __restrict__ bxt,
                            float* __restrict__ convb) {
    int j = blockIdx.x * blockDim.x + threadIdx.x;
    if (j >= NBATCH * 384) return;
    int b = j / 384, rem = j % 384;
    int o = rem / 12, h = rem % 12;
    float acc = bxt[o];
#pragma unroll
    for (int s = 0; s < CONV_KSPLIT; ++s)
        acc += partial[(((size_t)s * NBATCH + b) * 32 + o) * 12 + h];
    convb[j] = acc;
}

// ---------------- final: f2 reduce (8 splits + bias + relu) fused with [512,512]@[512,1] ----------------
__global__ void final_out_fused(const float* __restrict__ hpart, const float* __restrict__ bf2,
                                const float* __restrict__ Wo, const float* __restrict__ bo,
                                float* __restrict__ out, int n) {
    int row = blockIdx.x * (blockDim.x / 64) + (threadIdx.x / 64);
    int lane = threadIdx.x & 63;
    if (row >= NBATCH) return;
    float acc = 0.f;
    for (int k = lane; k < 512; k += 64) {
        float v = bf2[k];
#pragma unroll
        for (int s = 0; s < 8; ++s) v += hpart[((size_t)s * n + row) * 512 + k];
        v = fmaxf(v, 0.f);
        acc = fmaf(v, Wo[k], acc);
    }
#pragma unroll
    for (int off = 32; off > 0; off >>= 1) acc += __shfl_down(acc, off);
    if (lane == 0) out[row] = acc + bo[0];
}

extern "C" void kernel_launch(void* const* d_in, const int* in_sizes, int n_in,
                              void* d_out, int out_size, void* d_ws, size_t ws_size,
                              hipStream_t stream) {
    (void)in_sizes; (void)n_in; (void)out_size; (void)ws_size;
    const float* x     = (const float*)d_in[0];
    const int*   ei    = (const int*)d_in[1];
    const int*   batch = (const int*)d_in[2];
    const float* T     = (const float*)d_in[3];
    const float* W1 = (const float*)d_in[4];   const float* b1 = (const float*)d_in[5];
    const float* W2 = (const float*)d_in[6];   const float* b2 = (const float*)d_in[7];
    const float* W3 = (const float*)d_in[8];   const float* b3 = (const float*)d_in[9];
    const float* Wg1 = (const float*)d_in[10]; const float* bg1 = (const float*)d_in[11];
    const float* Wg2 = (const float*)d_in[12]; const float* bg2 = (const float*)d_in[13];
    const float* Kxt = (const float*)d_in[14]; const float* bxt = (const float*)d_in[15];
    const float* Wxt = (const float*)d_in[16]; const float* bxt2 = (const float*)d_in[17];
    const float* Wf1 = (const float*)d_in[18]; const float* bf1 = (const float*)d_in[19];
    const float* Wf2 = (const float*)d_in[20]; const float* bf2 = (const float*)d_in[21];
    const float* Wo = (const float*)d_in[22];  const float* bo = (const float*)d_in[23];
    const int* src = ei;
    const int* dst = ei + N_EDGESC;

    char* ws = (char*)d_ws;
    size_t off = 0;
    auto alloc = [&](size_t bytes) -> void* {
        void* p = ws + off;
        off += (bytes + 255) & ~(size_t)255;
        return p;
    };
    int*   deg      = (int*)alloc((size_t)N_NODESC * 4);
    float* dinv     = (float*)alloc((size_t)N_NODESC * 4);
    int*   row_ptr  = (int*)alloc((size_t)(N_NODESC + 1) * 4);
    int*   fillc    = (int*)alloc((size_t)N_NODESC * 4);
    int*   csr_src  = (int*)alloc((size_t)N_EDGESC * 4);
    int*   csums    = (int*)alloc((size_t)4096 * 4);
    float* g0       = (float*)alloc((size_t)NBATCH * 312 * 4);
    float* g1       = (float*)alloc((size_t)NBATCH * 1024 * 4);
    float* convb    = (float*)alloc((size_t)NBATCH * 384 * 4);
    float* xc       = (float*)alloc((size_t)NBATCH * 256 * 4);
    float* f1       = (float*)alloc((size_t)NBATCH * 1024 * 4);
    float* cpart    = (float*)alloc((size_t)CONV_KSPLIT * NBATCH * 32 * 12 * 4);
    float* hpart    = (float*)alloc((size_t)4 * NBATCH * 1024 * 4);   // 8MB: max NS*n*KO
    ushort* xbf     = (ushort*)alloc((size_t)N_NODESC * 80 * 2);   // x' (80) -> later h1' (80)
    ushort* aggbuf  = (ushort*)alloc((size_t)N_NODESC * 160 * 2);  // agg1/2 (80), agg3 (160)
    ushort* hbuf    = (ushort*)alloc((size_t)N_NODESC * 160 * 2);  // h2' (160)
    ushort* Wt1     = (ushort*)alloc((size_t)78 * 80 * 2);
    ushort* Wt2     = (ushort*)alloc((size_t)156 * 80 * 2);
    ushort* Wt3     = (ushort*)alloc((size_t)312 * 160 * 2);
    ushort* Kbf     = (ushort*)alloc((size_t)32 * 6016 * 2);
    float* out      = (float*)d_out;

    const int TPB = 256;

    // ---- graph structure + conversions (dinv fused into convert_x; weights in one kernel) ----
    zero2<<<divup(NBATCH * 312, TPB), TPB, 0, stream>>>(deg, N_NODESC, (int*)g0, NBATCH * 312);
    count_deg<<<divup(N_EDGESC, TPB), TPB, 0, stream>>>(dst, deg, N_EDGESC);
    convert_x_dinv<<<divup(N_NODESC * 80, TPB), TPB, 0, stream>>>(x, deg, dinv, xbf, N_NODESC, 78, 80);
    int nchunks = divup(N_NODESC, SCAN_CHUNK);
    scan_chunks<<<nchunks, 256, 0, stream>>>(deg, row_ptr, csums, N_NODESC);
    scan_sums<<<1, 64, 0, stream>>>(csums, nchunks);
    finalize_rowptr<<<divup(N_NODESC, TPB), TPB, 0, stream>>>(row_ptr, csums, fillc, N_NODESC, N_EDGESC);
    fill_csr<<<divup(N_EDGESC, TPB), TPB, 0, stream>>>(src, dst, fillc, csr_src, N_EDGESC);
    convert_weights<<<divup(261152, TPB), TPB, 0, stream>>>(W1, W2, W3, Kxt, Wt1, Wt2, Wt3, Kbf);

    // ---- GCN layer 1: agg(x') -> gemm(+bias+relu, *dinv) -> h1' (LD 80) ----
    gcn_gather_vec<80><<<divup(N_NODESC * 10, TPB), TPB, 0, stream>>>(
        xbf, row_ptr, csr_src, dinv, aggbuf, N_NODESC);
    gemm_mfma<78, 80, 78, 80, 2, true><<<divup(N_NODESC, 64) * 2, 256, 0, stream>>>(
        aggbuf, Wt1, b1, dinv, xbf, N_NODESC);   // h1' overwrites xbf

    // ---- GCN layer 2: agg(h1') -> gemm(*dinv) -> h2' (LD 160) ----
    gcn_gather_vec<80><<<divup(N_NODESC * 10, TPB), TPB, 0, stream>>>(
        xbf, row_ptr, csr_src, dinv, aggbuf, N_NODESC);
    gemm_mfma<78, 80, 156, 160, 3, true><<<divup(N_NODESC, 64) * 3, 256, 0, stream>>>(
        aggbuf, Wt2, b2, dinv, hbuf, N_NODESC);

    // ---- GCN layer 3: agg(h2') -> gemm + FUSED segment-max (XCD-chunked grid) ----
    gcn_gather_vec<160><<<divup(N_NODESC * 20, TPB), TPB, 0, stream>>>(
        hbuf, row_ptr, csr_src, dinv, aggbuf, N_NODESC);
    gemm_mfma_segmax<<<8 * 196 * 5, 256, 0, stream>>>(
        aggbuf, Wt3, b3, batch, (uint*)g0, N_NODESC);

    // ---- graph head: g1 = relu(g0 @ Wg1 + bg1) — 3 K-splits, 768 blocks ----
    gemm_head<312, 1024, 112><<<dim3(16, 16, 3), 256, 0, stream>>>(g0, Wg1, hpart, NBATCH);
    head_reduce<3, true><<<divup(NBATCH * 1024, TPB), TPB, 0, stream>>>(
        hpart, bg1, g1, NBATCH, 1024, 1024, 0);
    // xc[:, :128] = g1 @ Wg2 + bg2 — 16 K-splits, 512 blocks
    gemm_head<1024, 128, 64><<<dim3(16, 2, 16), 256, 0, stream>>>(g1, Wg2, hpart, NBATCH);
    head_reduce<16, false><<<divup(NBATCH * 128, TPB), TPB, 0, stream>>>(
        hpart, bg2, xc, NBATCH, 128, 256, 0);

    // ---- protein branch: implicit-GEMM conv via MFMA (coalesced region + LDS transpose) ----
    conv_mfma<<<dim3(6144 / 64, CONV_KSPLIT), 256, 0, stream>>>(T, Kbf, cpart);
    conv_reduce<<<divup(NBATCH * 384, TPB), TPB, 0, stream>>>(cpart, bxt, convb);
    // xc[:, 128:] = convb @ Wxt + bxt2 — 16 K-splits, 512 blocks
    gemm_head<384, 128, 24><<<dim3(16, 2, 16), 256, 0, stream>>>(convb, Wxt, hpart, NBATCH);
    head_reduce<16, false><<<divup(NBATCH * 128, TPB), TPB, 0, stream>>>(
        hpart, bxt2, xc, NBATCH, 128, 256, 128);

    // ---- fusion MLP: f1 — 4 K-splits, 1024 blocks; f2 fused into final ----
    gemm_head<256, 1024, 64><<<dim3(16, 16, 4), 256, 0, stream>>>(xc, Wf1, hpart, NBATCH);
    head_reduce<4, true><<<divup(NBATCH * 1024, TPB), TPB, 0, stream>>>(
        hpart, bf1, f1, NBATCH, 1024, 1024, 0);
    gemm_head<1024, 512, 128><<<dim3(16, 8, 8), 256, 0, stream>>>(f1, Wf2, hpart, NBATCH);
    final_out_fused<<<divup(NBATCH, 4), 256, 0, stream>>>(hpart, bf2, Wo, bo, out, NBATCH);
}